// Round 1
// baseline (776.837 us; speedup 1.0000x reference)
//
#include <hip/hip_runtime.h>
#include <hip/hip_bf16.h>
#include <math.h>

#define B_ 16
#define N_ 256
#define D_ 128
#define H_ 8
#define HD_ 16
#define EPS_ 1e-8f
#define PI_F 3.14159265358979323846f
#define TWO_PI_F 6.28318530717958647692f
#define INV_TWO_PI_F 0.15915494309189533577f

// ---------------- workspace layout (floats) ----------------
#define OFF_PT   0               // 4096
#define OFF_RAP  4096
#define OFF_PHI  8192
#define OFF_PX   12288
#define OFF_PY   16384
#define OFF_PZ   20480
#define OFF_E    24576
#define OFF_Q    28672           // 524288
#define OFF_K    (28672 + 524288)
#define OFF_V    (28672 + 2*524288)
#define OFF_BIAS (28672 + 3*524288)     // 8388608 floats (B,H,N,N)
#define OFF_AO   (OFF_BIAS + 8388608)   // 524288
// total = 10,514,432 floats = ~40.1 MB

// LDS layout for pair-MLP weights (floats)
#define SW0 0        // 4*64
#define SB0 256      // 64
#define SW1 320      // 64*64
#define SB1 4416     // 64
#define SW2 4480     // 64*64
#define SB2 8576     // 64
#define SW3 8640     // 64*8
#define SB3 9152     // 8
#define SH_TOT 9160

__device__ __forceinline__ float gelu_f(float x) {
    // tanh-approx gelu: 0.5x(1+tanh(sqrt(2/pi)(x+0.044715x^3)))
    //                 = x * (1 - 1/(exp(2t)+1))
    float x2 = x * x;
    float t = 0.7978845608028654f * x * fmaf(0.044715f, x2, 1.0f);
    float e = __expf(2.0f * t);          // overflow -> inf -> rcp -> 0 -> gelu = x
    return x * (1.0f - __builtin_amdgcn_rcpf(e + 1.0f));
}

// ---------------- K1: per-particle features ----------------
__global__ __launch_bounds__(256) void k_particle(const float* __restrict__ x_pf,
                                                  float* __restrict__ ws) {
    int idx = blockIdx.x * 256 + threadIdx.x;      // 0 .. 4095
    int b = idx >> 8, n = idx & 255;
    const float* base = x_pf + (size_t)b * 4 * N_;
    float px = base[0 * N_ + n];
    float py = base[1 * N_ + n];
    float pz = base[2 * N_ + n];
    float e  = base[3 * N_ + n];
    float pt  = sqrtf(fmaxf(px * px + py * py, EPS_));
    float rap = 0.5f * log1pf(2.0f * pz / fmaxf(e - pz, 1e-20f));
    float phi = atan2f(py, px);
    ws[OFF_PT  + idx] = pt;
    ws[OFF_RAP + idx] = rap;
    ws[OFF_PHI + idx] = phi;
    ws[OFF_PX  + idx] = px;
    ws[OFF_PY  + idx] = py;
    ws[OFF_PZ  + idx] = pz;
    ws[OFF_E   + idx] = e;
}

// ---------------- K2: pairwise features + MLP -> attn bias ----------------
__global__ __launch_bounds__(256) void k_pair_mlp(
    const float* __restrict__ ws,
    const float* __restrict__ w0, const float* __restrict__ b0,
    const float* __restrict__ w1, const float* __restrict__ b1,
    const float* __restrict__ w2, const float* __restrict__ b2,
    const float* __restrict__ w3, const float* __restrict__ b3,
    float* __restrict__ bias_out) {
    __shared__ float sh[SH_TOT];
    int tid = threadIdx.x;

    // cooperative weight staging (coalesced)
    if (tid < 256) sh[SW0 + tid] = w0[tid];
    for (int t = tid; t < 64; t += 256) {
        sh[SB0 + t] = b0[t];
        sh[SB1 + t] = b1[t];
        sh[SB2 + t] = b2[t];
    }
    for (int t = tid; t < 4096; t += 256) {
        sh[SW1 + t] = w1[t];
        sh[SW2 + t] = w2[t];
    }
    for (int t = tid; t < 512; t += 256) sh[SW3 + t] = w3[t];
    if (tid < 8) sh[SB3 + tid] = b3[tid];

    int row = blockIdx.x;            // b*N + i
    int b = row >> 8;
    int i = row & 255;
    int j = tid;
    int ib = row;                    // particle index of i
    int jb = (b << 8) + j;           // particle index of j

    // i-side loads are block-uniform (scalarized); j-side coalesced
    float pt_i = ws[OFF_PT + ib],  rap_i = ws[OFF_RAP + ib], phi_i = ws[OFF_PHI + ib];
    float px_i = ws[OFF_PX + ib],  py_i  = ws[OFF_PY  + ib];
    float pz_i = ws[OFF_PZ + ib],  e_i   = ws[OFF_E   + ib];
    float pt_j = ws[OFF_PT + jb],  rap_j = ws[OFF_RAP + jb], phi_j = ws[OFF_PHI + jb];
    float px_j = ws[OFF_PX + jb],  py_j  = ws[OFF_PY  + jb];
    float pz_j = ws[OFF_PZ + jb],  e_j   = ws[OFF_E   + jb];

    __syncthreads();

    float drap = rap_i - rap_j;
    float xw = phi_i - phi_j + PI_F;
    float mw = xw - TWO_PI_F * floorf(xw * INV_TWO_PI_F);   // python-style mod
    float dphi = mw - PI_F;
    float delta = sqrtf(drap * drap + dphi * dphi);
    float lndelta = __logf(fmaxf(delta, EPS_));
    float ptmin = fminf(pt_i, pt_j);
    float lnkt = __logf(fmaxf(ptmin * delta, EPS_));
    float lnz  = __logf(fmaxf(ptmin / fmaxf(pt_i + pt_j, EPS_), EPS_));
    float es = e_i + e_j, pxs = px_i + px_j, pys = py_i + py_j, pzs = pz_i + pz_j;
    float m2 = es * es - pxs * pxs - pys * pys - pzs * pzs;
    float lnm2 = __logf(fmaxf(m2, EPS_));

    float f0 = lnkt, f1 = lnz, f2 = lndelta, f3 = lnm2;

    // ---- layer 0: 4 -> 64, gelu ----
    float h[64];
#pragma unroll
    for (int o = 0; o < 64; ++o) {
        float a = sh[SB0 + o];
        a = fmaf(f0, sh[SW0 + o], a);
        a = fmaf(f1, sh[SW0 + 64 + o], a);
        a = fmaf(f2, sh[SW0 + 128 + o], a);
        a = fmaf(f3, sh[SW0 + 192 + o], a);
        h[o] = gelu_f(a);
    }

    // ---- layer 1: 64 -> 64, gelu ----
    float g[64];
#pragma unroll
    for (int o = 0; o < 64; ++o) g[o] = sh[SB1 + o];
#pragma unroll
    for (int k = 0; k < 64; ++k) {
        float hk = h[k];
#pragma unroll
        for (int o = 0; o < 64; ++o) g[o] = fmaf(hk, sh[SW1 + k * 64 + o], g[o]);
    }
#pragma unroll
    for (int o = 0; o < 64; ++o) g[o] = gelu_f(g[o]);

    // ---- layer 2: 64 -> 64, gelu (reuse h as accumulator) ----
#pragma unroll
    for (int o = 0; o < 64; ++o) h[o] = sh[SB2 + o];
#pragma unroll
    for (int k = 0; k < 64; ++k) {
        float gk = g[k];
#pragma unroll
        for (int o = 0; o < 64; ++o) h[o] = fmaf(gk, sh[SW2 + k * 64 + o], h[o]);
    }
#pragma unroll
    for (int o = 0; o < 64; ++o) h[o] = gelu_f(h[o]);

    // ---- layer 3: 64 -> 8, linear ----
    float y[8];
#pragma unroll
    for (int o = 0; o < 8; ++o) y[o] = sh[SB3 + o];
#pragma unroll
    for (int k = 0; k < 64; ++k) {
        float hk = h[k];
#pragma unroll
        for (int o = 0; o < 8; ++o) y[o] = fmaf(hk, sh[SW3 + k * 8 + o], y[o]);
    }

    // attn_bias layout (B,H,N,N)
#pragma unroll
    for (int o = 0; o < 8; ++o)
        bias_out[(((size_t)(b * H_ + o)) * N_ + i) * N_ + j] = y[o];
}

// ---------------- K3: QKV projection ----------------
__global__ __launch_bounds__(128) void k_qkv(
    const float* __restrict__ xf,
    const float* __restrict__ wq, const float* __restrict__ wk, const float* __restrict__ wv,
    const float* __restrict__ bq, const float* __restrict__ bk, const float* __restrict__ bv,
    float* __restrict__ ws) {
    __shared__ float lx[8 * 128];
    int o = threadIdx.x;
    int r0 = blockIdx.x * 8;                 // row = b*N+n
    for (int t = o; t < 1024; t += 128) lx[t] = xf[(size_t)r0 * 128 + t];
    __syncthreads();
    float aq[8], ak[8], av[8];
    float bqo = bq[o], bko = bk[o], bvo = bv[o];
#pragma unroll
    for (int r = 0; r < 8; ++r) { aq[r] = bqo; ak[r] = bko; av[r] = bvo; }
    for (int k = 0; k < 128; ++k) {
        float wqk = wq[k * 128 + o];
        float wkk = wk[k * 128 + o];
        float wvk = wv[k * 128 + o];
#pragma unroll
        for (int r = 0; r < 8; ++r) {
            float xv = lx[r * 128 + k];
            aq[r] = fmaf(xv, wqk, aq[r]);
            ak[r] = fmaf(xv, wkk, ak[r]);
            av[r] = fmaf(xv, wvk, av[r]);
        }
    }
#pragma unroll
    for (int r = 0; r < 8; ++r) {
        size_t off = ((size_t)(r0 + r)) * 128 + o;
        ws[OFF_Q + off] = aq[r];
        ws[OFF_K + off] = ak[r];
        ws[OFF_V + off] = av[r];
    }
}

// ---------------- K4: attention (one wave per (b,h,i) row) ----------------
__global__ __launch_bounds__(256) void k_attn(const float* __restrict__ ws,
                                              float* __restrict__ wso) {
    int gt = blockIdx.x * 256 + threadIdx.x;
    int wid = gt >> 6;                 // 0 .. 32767
    int lane = gt & 63;
    int b = wid >> 11;
    int r = wid & 2047;
    int h = r >> 8;
    int i = r & 255;

    const float4* q4 = reinterpret_cast<const float4*>(ws + OFF_Q + ((size_t)(b * N_ + i)) * D_ + h * HD_);
    float4 qa = q4[0], qb = q4[1], qc = q4[2], qd = q4[3];
    const float* kbp = ws + OFF_K + (size_t)b * N_ * D_ + h * HD_;
    const float* vbp = ws + OFF_V + (size_t)b * N_ * D_ + h * HD_;
    const float* brow = ws + OFF_BIAS + (((size_t)(b * H_ + h)) * N_ + i) * N_;

    float s[4];
#pragma unroll
    for (int t = 0; t < 4; ++t) {
        int j = lane + 64 * t;
        const float4* k4 = reinterpret_cast<const float4*>(kbp + (size_t)j * D_);
        float4 ka = k4[0], kb = k4[1], kc = k4[2], kd = k4[3];
        float dot;
        dot = qa.x * ka.x;
        dot = fmaf(qa.y, ka.y, dot); dot = fmaf(qa.z, ka.z, dot); dot = fmaf(qa.w, ka.w, dot);
        dot = fmaf(qb.x, kb.x, dot); dot = fmaf(qb.y, kb.y, dot);
        dot = fmaf(qb.z, kb.z, dot); dot = fmaf(qb.w, kb.w, dot);
        dot = fmaf(qc.x, kc.x, dot); dot = fmaf(qc.y, kc.y, dot);
        dot = fmaf(qc.z, kc.z, dot); dot = fmaf(qc.w, kc.w, dot);
        dot = fmaf(qd.x, kd.x, dot); dot = fmaf(qd.y, kd.y, dot);
        dot = fmaf(qd.z, kd.z, dot); dot = fmaf(qd.w, kd.w, dot);
        s[t] = fmaf(0.25f, dot, brow[j]);
    }
    float mx = fmaxf(fmaxf(s[0], s[1]), fmaxf(s[2], s[3]));
#pragma unroll
    for (int off = 32; off; off >>= 1) mx = fmaxf(mx, __shfl_xor(mx, off));
    float p[4], l = 0.0f;
#pragma unroll
    for (int t = 0; t < 4; ++t) { p[t] = __expf(s[t] - mx); l += p[t]; }
#pragma unroll
    for (int off = 32; off; off >>= 1) l += __shfl_xor(l, off);

    float acc[16];
#pragma unroll
    for (int d = 0; d < 16; ++d) acc[d] = 0.0f;
#pragma unroll
    for (int t = 0; t < 4; ++t) {
        int j = lane + 64 * t;
        const float4* v4 = reinterpret_cast<const float4*>(vbp + (size_t)j * D_);
        float4 va = v4[0], vb = v4[1], vc = v4[2], vd = v4[3];
        float pt = p[t];
        acc[0]  = fmaf(pt, va.x, acc[0]);  acc[1]  = fmaf(pt, va.y, acc[1]);
        acc[2]  = fmaf(pt, va.z, acc[2]);  acc[3]  = fmaf(pt, va.w, acc[3]);
        acc[4]  = fmaf(pt, vb.x, acc[4]);  acc[5]  = fmaf(pt, vb.y, acc[5]);
        acc[6]  = fmaf(pt, vb.z, acc[6]);  acc[7]  = fmaf(pt, vb.w, acc[7]);
        acc[8]  = fmaf(pt, vc.x, acc[8]);  acc[9]  = fmaf(pt, vc.y, acc[9]);
        acc[10] = fmaf(pt, vc.z, acc[10]); acc[11] = fmaf(pt, vc.w, acc[11]);
        acc[12] = fmaf(pt, vd.x, acc[12]); acc[13] = fmaf(pt, vd.y, acc[13]);
        acc[14] = fmaf(pt, vd.w == vd.w ? vd.z : vd.z, acc[14]); // vd.z (keep simple)
        acc[15] = fmaf(pt, vd.w, acc[15]);
    }
#pragma unroll
    for (int d = 0; d < 16; ++d) {
#pragma unroll
        for (int off = 32; off; off >>= 1) acc[d] += __shfl_xor(acc[d], off);
    }
    if (lane == 0) {
        float invl = 1.0f / l;
        float* op = wso + OFF_AO + ((size_t)(b * N_ + i)) * D_ + h * HD_;
#pragma unroll
        for (int d = 0; d < 16; ++d) op[d] = acc[d] * invl;
    }
}

// ---------------- K5: output projection ----------------
__global__ __launch_bounds__(128) void k_out(const float* __restrict__ ws,
                                             const float* __restrict__ wo,
                                             const float* __restrict__ bo,
                                             float* __restrict__ out) {
    __shared__ float lx[8 * 128];
    int o = threadIdx.x;
    int r0 = blockIdx.x * 8;
    for (int t = o; t < 1024; t += 128) lx[t] = ws[OFF_AO + (size_t)r0 * 128 + t];
    __syncthreads();
    float acc[8];
    float boo = bo[o];
#pragma unroll
    for (int r = 0; r < 8; ++r) acc[r] = boo;
    for (int k = 0; k < 128; ++k) {
        float w = wo[k * 128 + o];
#pragma unroll
        for (int r = 0; r < 8; ++r) acc[r] = fmaf(lx[r * 128 + k], w, acc[r]);
    }
#pragma unroll
    for (int r = 0; r < 8; ++r) out[((size_t)(r0 + r)) * 128 + o] = acc[r];
}

extern "C" void kernel_launch(void* const* d_in, const int* in_sizes, int n_in,
                              void* d_out, int out_size, void* d_ws, size_t ws_size,
                              hipStream_t stream) {
    const float* x_pf   = (const float*)d_in[0];
    const float* x_feat = (const float*)d_in[1];
    const float* w0 = (const float*)d_in[2];
    const float* b0 = (const float*)d_in[3];
    const float* w1 = (const float*)d_in[4];
    const float* b1 = (const float*)d_in[5];
    const float* w2 = (const float*)d_in[6];
    const float* b2 = (const float*)d_in[7];
    const float* w3 = (const float*)d_in[8];
    const float* b3 = (const float*)d_in[9];
    const float* wq = (const float*)d_in[10];
    const float* wk = (const float*)d_in[11];
    const float* wv = (const float*)d_in[12];
    const float* wo = (const float*)d_in[13];
    const float* bq = (const float*)d_in[14];
    const float* bk = (const float*)d_in[15];
    const float* bv = (const float*)d_in[16];
    const float* bo = (const float*)d_in[17];
    float* ws  = (float*)d_ws;
    float* out = (float*)d_out;

    hipLaunchKernelGGL(k_particle, dim3(16), dim3(256), 0, stream, x_pf, ws);
    hipLaunchKernelGGL(k_pair_mlp, dim3(B_ * N_), dim3(256), 0, stream,
                       ws, w0, b0, w1, b1, w2, b2, w3, b3, ws + OFF_BIAS);
    hipLaunchKernelGGL(k_qkv, dim3(512), dim3(128), 0, stream,
                       x_feat, wq, wk, wv, bq, bk, bv, ws);
    hipLaunchKernelGGL(k_attn, dim3(8192), dim3(256), 0, stream, ws, ws);
    hipLaunchKernelGGL(k_out, dim3(512), dim3(128), 0, stream, ws, wo, bo, out);
}

// Round 3
// 464.335 us; speedup vs baseline: 1.6730x; 1.6730x over previous
//
#include <hip/hip_runtime.h>
#include <hip/hip_bf16.h>
#include <math.h>

#define B_ 16
#define N_ 256
#define D_ 128
#define H_ 8
#define HD_ 16
#define EPS_ 1e-8f
#define PI_F 3.14159265358979323846f
#define TWO_PI_F 6.28318530717958647692f
#define INV_TWO_PI_F 0.15915494309189533577f

// ---------------- workspace layout (float units) ----------------
#define OFF_PT   0               // 4096
#define OFF_RAP  4096
#define OFF_PHI  8192
#define OFF_PX   12288
#define OFF_PY   16384
#define OFF_PZ   20480
#define OFF_E    24576
#define OFF_Q    28672           // 524288
#define OFF_K    (28672 + 524288)
#define OFF_V    (28672 + 2*524288)
#define OFF_BIAS (28672 + 3*524288)     // 8388608 floats (B,H,N,N)
#define OFF_AO   (OFF_BIAS + 8388608)   // 524288
#define OFF_WPACK (OFF_AO + 524288)     // packed bf16 weight frags (ushort region)

// packed weight-frag offsets (ushort units, relative to wp)
#define UA0  0        // 2048  : layer0 combined hi/lo k-slot packing
#define UA1H 2048     // 4096
#define UA1L 6144     // 4096
#define UA2H 10240    // 4096
#define UA2L 14336    // 4096
#define UA3H 18432    // 1024
#define UA3L 19456    // 1024
// total 20480 ushorts = 40 KB

typedef __attribute__((ext_vector_type(8))) short s8;       // 8 bf16 (4 VGPR)
typedef __attribute__((ext_vector_type(4))) float f4;       // MFMA C/D
typedef __attribute__((ext_vector_type(4))) unsigned int u4;
typedef __attribute__((ext_vector_type(4))) unsigned short us4;

__device__ __forceinline__ unsigned short bf16h(float x) {
    unsigned u = __builtin_bit_cast(unsigned, x);
    unsigned r = (u + 0x7fffu + ((u >> 16) & 1u)) >> 16;
    return (unsigned short)r;
}
__device__ __forceinline__ float bf16tof(unsigned short h) {
    unsigned u = ((unsigned)h) << 16;
    return __builtin_bit_cast(float, u);
}

__device__ __forceinline__ float gelu_f(float x) {
    // tanh-approx gelu == x * sigmoid(2t),  t = sqrt(2/pi)(x + 0.044715 x^3)
    float x2 = x * x;
    float t = 0.7978845608028654f * x * fmaf(0.044715f, x2, 1.0f);
    float e = __expf(2.0f * t);          // inf-safe: rcp(inf)=0 -> gelu=x
    return x * (1.0f - __builtin_amdgcn_rcpf(e + 1.0f));
}

// ---------------- K0: pack pair-MLP weights into MFMA A-fragments (hi/lo bf16) ----------------
__global__ __launch_bounds__(256) void k_prep(
    const float* __restrict__ w0, const float* __restrict__ w1,
    const float* __restrict__ w2, const float* __restrict__ w3,
    unsigned short* __restrict__ wp) {
    int t = threadIdx.x;
    // layer0 k-slot packing: A slots 0-3 = Wh, 4-7 = Wh (pairs with Fl), 8-11 = Wl, 12-31 = 0
    for (int e = t; e < 2048; e += 256) {
        int fi = e >> 3, j = e & 7;
        int mt = fi >> 6, lane = fi & 63;
        int q = lane >> 4, ln = lane & 15;
        int s = q * 8 + j;
        int m = mt * 16 + ln;
        unsigned short v = 0;
        if (s < 4) v = bf16h(w0[s * 64 + m]);
        else if (s < 8) v = bf16h(w0[(s - 4) * 64 + m]);
        else if (s < 12) {
            float x = w0[(s - 8) * 64 + m];
            v = bf16h(x - bf16tof(bf16h(x)));
        }
        wp[UA0 + e] = v;
    }
    // layers 1,2: A[m=out][k=in] frags, frag fi=(mt*2+ks)*64+lane, elem j -> k=ks*32+(lane>>4)*8+j
    for (int e = t; e < 4096; e += 256) {
        int fi = e >> 3, j = e & 7;
        int mt = fi >> 7, ks = (fi >> 6) & 1, lane = fi & 63;
        int k = ks * 32 + ((lane >> 4) << 3) + j;
        int m = mt * 16 + (lane & 15);
        float x1 = w1[k * 64 + m];
        unsigned short h1 = bf16h(x1);
        wp[UA1H + e] = h1;
        wp[UA1L + e] = bf16h(x1 - bf16tof(h1));
        float x2 = w2[k * 64 + m];
        unsigned short h2 = bf16h(x2);
        wp[UA2H + e] = h2;
        wp[UA2L + e] = bf16h(x2 - bf16tof(h2));
    }
    // layer3: single m-tile (rows 8..15 zero)
    for (int e = t; e < 1024; e += 256) {
        int fi = e >> 3, j = e & 7;
        int ks = fi >> 6, lane = fi & 63;
        int k = ks * 32 + ((lane >> 4) << 3) + j;
        int m = lane & 15;
        float x = (m < 8) ? w3[k * 8 + m] : 0.0f;
        unsigned short h = bf16h(x);
        wp[UA3H + e] = h;
        wp[UA3L + e] = bf16h(x - bf16tof(h));
    }
}

// ---------------- K1: per-particle features ----------------
__global__ __launch_bounds__(256) void k_particle(const float* __restrict__ x_pf,
                                                  float* __restrict__ ws) {
    int idx = blockIdx.x * 256 + threadIdx.x;      // 0 .. 4095
    int b = idx >> 8, n = idx & 255;
    const float* base = x_pf + (size_t)b * 4 * N_;
    float px = base[0 * N_ + n];
    float py = base[1 * N_ + n];
    float pz = base[2 * N_ + n];
    float e  = base[3 * N_ + n];
    float pt  = sqrtf(fmaxf(px * px + py * py, EPS_));
    float rap = 0.5f * log1pf(2.0f * pz / fmaxf(e - pz, 1e-20f));
    float phi = atan2f(py, px);
    ws[OFF_PT  + idx] = pt;
    ws[OFF_RAP + idx] = rap;
    ws[OFF_PHI + idx] = phi;
    ws[OFF_PX  + idx] = px;
    ws[OFF_PY  + idx] = py;
    ws[OFF_PZ  + idx] = pz;
    ws[OFF_E   + idx] = e;
}

// ---------------- K2: pairwise features + split-bf16 MFMA MLP -> attn bias ----------------
// grid: 8192 blocks = (b,i) x 2 j-halves; block = 128 threads = 2 independent waves x 64 pairs
__global__ __launch_bounds__(128, 2) void k_pair_mlp(
    const float* __restrict__ ws, const unsigned short* __restrict__ wp,
    const float* __restrict__ b0g, const float* __restrict__ b1g,
    const float* __restrict__ b2g, const float* __restrict__ b3g,
    float* __restrict__ bias_out) {
    // activations [pair][72] bf16 (pad 64->72 keeps 16B alignment + 2-way-only bank alias)
    __shared__ __align__(16) unsigned short actH[128 * 72];
    __shared__ __align__(16) unsigned short actL[128 * 72];
    __shared__ __align__(16) unsigned short Ffrag[128 * 40];

    int tid = threadIdx.x;
    int lane = tid & 63;
    int ln = lane & 15, q = lane >> 4;
    int pb = (tid >> 6) * 64;               // wave's pair base within the block
    int j0 = (blockIdx.x & 1) * 128;
    int row = blockIdx.x >> 1;              // b*N + i
    int b = row >> 8, i = row & 255;

    // ---- phase 0: features for pair p = tid (j = j0 + tid) ----
    {
        int ib = row;
        int jb = (b << 8) + j0 + tid;
        float pt_i = ws[OFF_PT + ib],  rap_i = ws[OFF_RAP + ib], phi_i = ws[OFF_PHI + ib];
        float px_i = ws[OFF_PX + ib],  py_i  = ws[OFF_PY  + ib];
        float pz_i = ws[OFF_PZ + ib],  e_i   = ws[OFF_E   + ib];
        float pt_j = ws[OFF_PT + jb],  rap_j = ws[OFF_RAP + jb], phi_j = ws[OFF_PHI + jb];
        float px_j = ws[OFF_PX + jb],  py_j  = ws[OFF_PY  + jb];
        float pz_j = ws[OFF_PZ + jb],  e_j   = ws[OFF_E   + jb];

        float drap = rap_i - rap_j;
        float xw = phi_i - phi_j + PI_F;
        float mw = xw - TWO_PI_F * floorf(xw * INV_TWO_PI_F);
        float dphi = mw - PI_F;
        float delta = sqrtf(drap * drap + dphi * dphi);
        float f2 = __logf(fmaxf(delta, EPS_));                         // lndelta
        float ptmin = fminf(pt_i, pt_j);
        float f0 = __logf(fmaxf(ptmin * delta, EPS_));                 // lnkt
        float f1 = __logf(fmaxf(ptmin / fmaxf(pt_i + pt_j, EPS_), EPS_)); // lnz
        float es = e_i + e_j, pxs = px_i + px_j, pys = py_i + py_j, pzs = pz_i + pz_j;
        float f3 = __logf(fmaxf(es * es - pxs * pxs - pys * pys - pzs * pzs, EPS_)); // lnm2

        unsigned short h0 = bf16h(f0), h1 = bf16h(f1), h2 = bf16h(f2), h3 = bf16h(f3);
        unsigned short l0 = bf16h(f0 - bf16tof(h0));
        unsigned short l1 = bf16h(f1 - bf16tof(h1));
        unsigned short l2 = bf16h(f2 - bf16tof(h2));
        unsigned short l3 = bf16h(f3 - bf16tof(h3));
        unsigned ph01 = (unsigned)h0 | ((unsigned)h1 << 16);
        unsigned ph23 = (unsigned)h2 | ((unsigned)h3 << 16);
        unsigned pl01 = (unsigned)l0 | ((unsigned)l1 << 16);
        unsigned pl23 = (unsigned)l2 | ((unsigned)l3 << 16);
        u4 s07 = { ph01, ph23, pl01, pl23 };   // slots 0-7:  Fh | Fl
        u4 s815 = { ph01, ph23, 0u, 0u };      // slots 8-15: Fh | 0
        u4 z = { 0u, 0u, 0u, 0u };
        *(u4*)&Ffrag[tid * 40 + 0]  = s07;
        *(u4*)&Ffrag[tid * 40 + 8]  = s815;
        *(u4*)&Ffrag[tid * 40 + 16] = z;       // slots 16-23
        *(u4*)&Ffrag[tid * 40 + 24] = z;       // slots 24-31
    }
    __syncthreads();

    f4 acc[4][4];
    const f4 zero4 = { 0.f, 0.f, 0.f, 0.f };

    // ---- layer 0: 4 -> 64 (single MFMA per tile via k-slot packed hi/lo) ----
#pragma unroll
    for (int mt = 0; mt < 4; ++mt)
#pragma unroll
        for (int nt = 0; nt < 4; ++nt) acc[mt][nt] = zero4;
    {
        s8 a0[4];
#pragma unroll
        for (int mt = 0; mt < 4; ++mt)
            a0[mt] = *(const s8*)&wp[UA0 + (mt * 64 + lane) * 8];
#pragma unroll
        for (int nt = 0; nt < 4; ++nt) {
            int pr = pb + nt * 16 + ln;
            s8 bf = *(const s8*)&Ffrag[pr * 40 + q * 8];
#pragma unroll
            for (int mt = 0; mt < 4; ++mt)
                acc[mt][nt] = __builtin_amdgcn_mfma_f32_16x16x32_bf16(a0[mt], bf, acc[mt][nt], 0, 0, 0);
        }
    }
    // epilogue: bias + gelu + hi/lo split -> act LDS
    {
#pragma unroll
        for (int mt = 0; mt < 4; ++mt) {
            f4 bv = *(const f4*)&b0g[mt * 16 + q * 4];
#pragma unroll
            for (int nt = 0; nt < 4; ++nt) {
                f4 g;
#pragma unroll
                for (int r = 0; r < 4; ++r) g[r] = gelu_f(acc[mt][nt][r] + bv[r]);
                us4 hs, lsv;
#pragma unroll
                for (int r = 0; r < 4; ++r) {
                    hs[r] = bf16h(g[r]);
                    lsv[r] = bf16h(g[r] - bf16tof(hs[r]));
                }
                int aoff = (pb + nt * 16 + ln) * 72 + mt * 16 + q * 4;
                *(us4*)&actH[aoff] = hs;
                *(us4*)&actL[aoff] = lsv;
            }
        }
    }

    // ---- layers 1 & 2: 64 -> 64, split-bf16 (3 MFMAs per nominal) ----
#pragma unroll 1
    for (int L = 0; L < 2; ++L) {
        const unsigned short* wh = (L == 0) ? (wp + UA1H) : (wp + UA2H);
        const unsigned short* wl = (L == 0) ? (wp + UA1L) : (wp + UA2L);
        const float* bg = (L == 0) ? b1g : b2g;
        s8 ah[4][2], al[4][2];
#pragma unroll
        for (int mt = 0; mt < 4; ++mt)
#pragma unroll
            for (int ks = 0; ks < 2; ++ks) {
                int fo = ((mt * 2 + ks) * 64 + lane) * 8;
                ah[mt][ks] = *(const s8*)&wh[fo];
                al[mt][ks] = *(const s8*)&wl[fo];
            }
#pragma unroll
        for (int mt = 0; mt < 4; ++mt)
#pragma unroll
            for (int nt = 0; nt < 4; ++nt) acc[mt][nt] = zero4;
#pragma unroll
        for (int nt = 0; nt < 4; ++nt) {
            int ro = (pb + nt * 16 + ln) * 72 + q * 8;
            s8 bh0 = *(const s8*)&actH[ro];
            s8 bh1 = *(const s8*)&actH[ro + 32];
            s8 bl0 = *(const s8*)&actL[ro];
            s8 bl1 = *(const s8*)&actL[ro + 32];
#pragma unroll
            for (int mt = 0; mt < 4; ++mt) {
                f4 c = acc[mt][nt];
                c = __builtin_amdgcn_mfma_f32_16x16x32_bf16(ah[mt][0], bh0, c, 0, 0, 0);
                c = __builtin_amdgcn_mfma_f32_16x16x32_bf16(ah[mt][0], bl0, c, 0, 0, 0);
                c = __builtin_amdgcn_mfma_f32_16x16x32_bf16(al[mt][0], bh0, c, 0, 0, 0);
                c = __builtin_amdgcn_mfma_f32_16x16x32_bf16(ah[mt][1], bh1, c, 0, 0, 0);
                c = __builtin_amdgcn_mfma_f32_16x16x32_bf16(ah[mt][1], bl1, c, 0, 0, 0);
                c = __builtin_amdgcn_mfma_f32_16x16x32_bf16(al[mt][1], bh1, c, 0, 0, 0);
                acc[mt][nt] = c;
            }
        }
        // epilogue (all LDS reads of this layer precede these writes -> in-place safe)
#pragma unroll
        for (int mt = 0; mt < 4; ++mt) {
            f4 bv = *(const f4*)&bg[mt * 16 + q * 4];
#pragma unroll
            for (int nt = 0; nt < 4; ++nt) {
                f4 g;
#pragma unroll
                for (int r = 0; r < 4; ++r) g[r] = gelu_f(acc[mt][nt][r] + bv[r]);
                us4 hs, lsv;
#pragma unroll
                for (int r = 0; r < 4; ++r) {
                    hs[r] = bf16h(g[r]);
                    lsv[r] = bf16h(g[r] - bf16tof(hs[r]));
                }
                int aoff = (pb + nt * 16 + ln) * 72 + mt * 16 + q * 4;
                *(us4*)&actH[aoff] = hs;
                *(us4*)&actL[aoff] = lsv;
            }
        }
    }

    // ---- layer 3: 64 -> 8 (one padded m-tile) ----
    {
        s8 a3h[2], a3l[2];
#pragma unroll
        for (int ks = 0; ks < 2; ++ks) {
            int fo = (ks * 64 + lane) * 8;
            a3h[ks] = *(const s8*)&wp[UA3H + fo];
            a3l[ks] = *(const s8*)&wp[UA3L + fo];
        }
        f4 acc3[4];
#pragma unroll
        for (int nt = 0; nt < 4; ++nt) acc3[nt] = zero4;
#pragma unroll
        for (int nt = 0; nt < 4; ++nt) {
            int ro = (pb + nt * 16 + ln) * 72 + q * 8;
            s8 bh0 = *(const s8*)&actH[ro];
            s8 bh1 = *(const s8*)&actH[ro + 32];
            s8 bl0 = *(const s8*)&actL[ro];
            s8 bl1 = *(const s8*)&actL[ro + 32];
            f4 c = acc3[nt];
            c = __builtin_amdgcn_mfma_f32_16x16x32_bf16(a3h[0], bh0, c, 0, 0, 0);
            c = __builtin_amdgcn_mfma_f32_16x16x32_bf16(a3h[0], bl0, c, 0, 0, 0);
            c = __builtin_amdgcn_mfma_f32_16x16x32_bf16(a3l[0], bh0, c, 0, 0, 0);
            c = __builtin_amdgcn_mfma_f32_16x16x32_bf16(a3h[1], bh1, c, 0, 0, 0);
            c = __builtin_amdgcn_mfma_f32_16x16x32_bf16(a3h[1], bl1, c, 0, 0, 0);
            c = __builtin_amdgcn_mfma_f32_16x16x32_bf16(a3l[1], bh1, c, 0, 0, 0);
            acc3[nt] = c;
        }
        if (q < 2) {                       // rows 0-7 hold the H=8 outputs
            f4 b3v = *(const f4*)&b3g[q * 4];
#pragma unroll
            for (int nt = 0; nt < 4; ++nt) {
                int jc = j0 + pb + nt * 16 + ln;   // FIX: include wave base pb
#pragma unroll
                for (int r = 0; r < 4; ++r) {
                    int out = q * 4 + r;
                    bias_out[(((size_t)(b * H_ + out)) * N_ + i) * N_ + jc] = acc3[nt][r] + b3v[r];
                }
            }
        }
    }
}

// ---------------- K3: QKV projection ----------------
__global__ __launch_bounds__(128) void k_qkv(
    const float* __restrict__ xf,
    const float* __restrict__ wq, const float* __restrict__ wk, const float* __restrict__ wv,
    const float* __restrict__ bq, const float* __restrict__ bk, const float* __restrict__ bv,
    float* __restrict__ ws) {
    __shared__ float lx[8 * 128];
    int o = threadIdx.x;
    int r0 = blockIdx.x * 8;                 // row = b*N+n
    for (int t = o; t < 1024; t += 128) lx[t] = xf[(size_t)r0 * 128 + t];
    __syncthreads();
    float aq[8], ak[8], av[8];
    float bqo = bq[o], bko = bk[o], bvo = bv[o];
#pragma unroll
    for (int r = 0; r < 8; ++r) { aq[r] = bqo; ak[r] = bko; av[r] = bvo; }
    for (int k = 0; k < 128; ++k) {
        float wqk = wq[k * 128 + o];
        float wkk = wk[k * 128 + o];
        float wvk = wv[k * 128 + o];
#pragma unroll
        for (int r = 0; r < 8; ++r) {
            float xv = lx[r * 128 + k];
            aq[r] = fmaf(xv, wqk, aq[r]);
            ak[r] = fmaf(xv, wkk, ak[r]);
            av[r] = fmaf(xv, wvk, av[r]);
        }
    }
#pragma unroll
    for (int r = 0; r < 8; ++r) {
        size_t off = ((size_t)(r0 + r)) * 128 + o;
        ws[OFF_Q + off] = aq[r];
        ws[OFF_K + off] = ak[r];
        ws[OFF_V + off] = av[r];
    }
}

// ---------------- K4: attention (one wave per (b,h,i) row) ----------------
__global__ __launch_bounds__(256) void k_attn(const float* __restrict__ ws,
                                              float* __restrict__ wso) {
    int gt = blockIdx.x * 256 + threadIdx.x;
    int wid = gt >> 6;                 // 0 .. 32767
    int lane = gt & 63;
    int b = wid >> 11;
    int r = wid & 2047;
    int h = r >> 8;
    int i = r & 255;

    const float4* q4 = reinterpret_cast<const float4*>(ws + OFF_Q + ((size_t)(b * N_ + i)) * D_ + h * HD_);
    float4 qa = q4[0], qb = q4[1], qc = q4[2], qd = q4[3];
    const float* kbp = ws + OFF_K + (size_t)b * N_ * D_ + h * HD_;
    const float* vbp = ws + OFF_V + (size_t)b * N_ * D_ + h * HD_;
    const float* brow = ws + OFF_BIAS + (((size_t)(b * H_ + h)) * N_ + i) * N_;

    float s[4];
#pragma unroll
    for (int t = 0; t < 4; ++t) {
        int j = lane + 64 * t;
        const float4* k4 = reinterpret_cast<const float4*>(kbp + (size_t)j * D_);
        float4 ka = k4[0], kb = k4[1], kc = k4[2], kd = k4[3];
        float dot;
        dot = qa.x * ka.x;
        dot = fmaf(qa.y, ka.y, dot); dot = fmaf(qa.z, ka.z, dot); dot = fmaf(qa.w, ka.w, dot);
        dot = fmaf(qb.x, kb.x, dot); dot = fmaf(qb.y, kb.y, dot);
        dot = fmaf(qb.z, kb.z, dot); dot = fmaf(qb.w, kb.w, dot);
        dot = fmaf(qc.x, kc.x, dot); dot = fmaf(qc.y, kc.y, dot);
        dot = fmaf(qc.z, kc.z, dot); dot = fmaf(qc.w, kc.w, dot);
        dot = fmaf(qd.x, kd.x, dot); dot = fmaf(qd.y, kd.y, dot);
        dot = fmaf(qd.z, kd.z, dot); dot = fmaf(qd.w, kd.w, dot);
        s[t] = fmaf(0.25f, dot, brow[j]);
    }
    float mx = fmaxf(fmaxf(s[0], s[1]), fmaxf(s[2], s[3]));
#pragma unroll
    for (int off = 32; off; off >>= 1) mx = fmaxf(mx, __shfl_xor(mx, off));
    float p[4], l = 0.0f;
#pragma unroll
    for (int t = 0; t < 4; ++t) { p[t] = __expf(s[t] - mx); l += p[t]; }
#pragma unroll
    for (int off = 32; off; off >>= 1) l += __shfl_xor(l, off);

    float acc[16];
#pragma unroll
    for (int d = 0; d < 16; ++d) acc[d] = 0.0f;
#pragma unroll
    for (int t = 0; t < 4; ++t) {
        int j = lane + 64 * t;
        const float4* v4 = reinterpret_cast<const float4*>(vbp + (size_t)j * D_);
        float4 va = v4[0], vb = v4[1], vc = v4[2], vd = v4[3];
        float pt = p[t];
        acc[0]  = fmaf(pt, va.x, acc[0]);  acc[1]  = fmaf(pt, va.y, acc[1]);
        acc[2]  = fmaf(pt, va.z, acc[2]);  acc[3]  = fmaf(pt, va.w, acc[3]);
        acc[4]  = fmaf(pt, vb.x, acc[4]);  acc[5]  = fmaf(pt, vb.y, acc[5]);
        acc[6]  = fmaf(pt, vb.z, acc[6]);  acc[7]  = fmaf(pt, vb.w, acc[7]);
        acc[8]  = fmaf(pt, vc.x, acc[8]);  acc[9]  = fmaf(pt, vc.y, acc[9]);
        acc[10] = fmaf(pt, vc.z, acc[10]); acc[11] = fmaf(pt, vc.w, acc[11]);
        acc[12] = fmaf(pt, vd.x, acc[12]); acc[13] = fmaf(pt, vd.y, acc[13]);
        acc[14] = fmaf(pt, vd.z, acc[14]); acc[15] = fmaf(pt, vd.w, acc[15]);
    }
#pragma unroll
    for (int d = 0; d < 16; ++d) {
#pragma unroll
        for (int off = 32; off; off >>= 1) acc[d] += __shfl_xor(acc[d], off);
    }
    if (lane == 0) {
        float invl = 1.0f / l;
        float* op = wso + OFF_AO + ((size_t)(b * N_ + i)) * D_ + h * HD_;
#pragma unroll
        for (int d = 0; d < 16; ++d) op[d] = acc[d] * invl;
    }
}

// ---------------- K5: output projection ----------------
__global__ __launch_bounds__(128) void k_out(const float* __restrict__ ws,
                                             const float* __restrict__ wo,
                                             const float* __restrict__ bo,
                                             float* __restrict__ out) {
    __shared__ float lx[8 * 128];
    int o = threadIdx.x;
    int r0 = blockIdx.x * 8;
    for (int t = o; t < 1024; t += 128) lx[t] = ws[OFF_AO + (size_t)r0 * 128 + t];
    __syncthreads();
    float acc[8];
    float boo = bo[o];
#pragma unroll
    for (int r = 0; r < 8; ++r) acc[r] = boo;
    for (int k = 0; k < 128; ++k) {
        float w = wo[k * 128 + o];
#pragma unroll
        for (int r = 0; r < 8; ++r) acc[r] = fmaf(lx[r * 128 + k], w, acc[r]);
    }
#pragma unroll
    for (int r = 0; r < 8; ++r) out[((size_t)(r0 + r)) * 128 + o] = acc[r];
}

extern "C" void kernel_launch(void* const* d_in, const int* in_sizes, int n_in,
                              void* d_out, int out_size, void* d_ws, size_t ws_size,
                              hipStream_t stream) {
    const float* x_pf   = (const float*)d_in[0];
    const float* x_feat = (const float*)d_in[1];
    const float* w0 = (const float*)d_in[2];
    const float* b0 = (const float*)d_in[3];
    const float* w1 = (const float*)d_in[4];
    const float* b1 = (const float*)d_in[5];
    const float* w2 = (const float*)d_in[6];
    const float* b2 = (const float*)d_in[7];
    const float* w3 = (const float*)d_in[8];
    const float* b3 = (const float*)d_in[9];
    const float* wq = (const float*)d_in[10];
    const float* wk = (const float*)d_in[11];
    const float* wv = (const float*)d_in[12];
    const float* wo = (const float*)d_in[13];
    const float* bq = (const float*)d_in[14];
    const float* bk = (const float*)d_in[15];
    const float* bv = (const float*)d_in[16];
    const float* bo = (const float*)d_in[17];
    float* ws  = (float*)d_ws;
    float* out = (float*)d_out;
    unsigned short* wpack = (unsigned short*)(ws + OFF_WPACK);

    hipLaunchKernelGGL(k_prep, dim3(1), dim3(256), 0, stream, w0, w1, w2, w3, wpack);
    hipLaunchKernelGGL(k_particle, dim3(16), dim3(256), 0, stream, x_pf, ws);
    hipLaunchKernelGGL(k_pair_mlp, dim3(B_ * N_ * 2), dim3(128), 0, stream,
                       ws, wpack, b0, b1, b2, b3, ws + OFF_BIAS);
    hipLaunchKernelGGL(k_qkv, dim3(512), dim3(128), 0, stream,
                       x_feat, wq, wk, wv, bq, bk, bv, ws);
    hipLaunchKernelGGL(k_attn, dim3(8192), dim3(256), 0, stream, ws, ws);
    hipLaunchKernelGGL(k_out, dim3(512), dim3(128), 0, stream, ws, wo, bo, out);
}

// Round 4
// 293.899 us; speedup vs baseline: 2.6432x; 1.5799x over previous
//
#include <hip/hip_runtime.h>
#include <hip/hip_bf16.h>
#include <math.h>

#define B_ 16
#define N_ 256
#define D_ 128
#define H_ 8
#define HD_ 16
#define EPS_ 1e-8f
#define PI_F 3.14159265358979323846f
#define TWO_PI_F 6.28318530717958647692f
#define INV_TWO_PI_F 0.15915494309189533577f

// ---------------- workspace layout (float units) ----------------
#define OFF_PT   0               // 4096
#define OFF_RAP  4096
#define OFF_PHI  8192
#define OFF_PX   12288
#define OFF_PY   16384
#define OFF_PZ   20480
#define OFF_E    24576
#define OFF_Q    28672           // 524288
#define OFF_K    (28672 + 524288)
#define OFF_V    (28672 + 2*524288)
#define OFF_BIAS (28672 + 3*524288)     // 8388608 floats (B,H,N,N)
#define OFF_AO   (OFF_BIAS + 8388608)   // 524288
#define OFF_WPACK (OFF_AO + 524288)     // packed bf16 weight frags (ushort region)

// packed weight-frag offsets (ushort units, relative to wp)
#define UA0  0        // 2048  : layer0 combined hi/lo k-slot packing
#define UA1H 2048     // 4096
#define UA1L 6144     // 4096
#define UA2H 10240    // 4096
#define UA2L 14336    // 4096
#define UA3H 18432    // 1024
#define UA3L 19456    // 1024

typedef __attribute__((ext_vector_type(8))) short s8;       // 8 bf16 (4 VGPR)
typedef __attribute__((ext_vector_type(4))) float f4;       // MFMA C/D
typedef __attribute__((ext_vector_type(4))) unsigned int u4;

__device__ __forceinline__ unsigned short bf16h(float x) {
    unsigned u = __builtin_bit_cast(unsigned, x);
    unsigned r = (u + 0x7fffu + ((u >> 16) & 1u)) >> 16;
    return (unsigned short)r;
}
__device__ __forceinline__ float bf16tof(unsigned short h) {
    unsigned u = ((unsigned)h) << 16;
    return __builtin_bit_cast(float, u);
}
// pack hi-bf16 (truncation) of two floats: low short = a, high short = b
__device__ __forceinline__ unsigned pack_hi2(float a, float b) {
    unsigned ua = __builtin_bit_cast(unsigned, a);
    unsigned ub = __builtin_bit_cast(unsigned, b);
    return (ua >> 16) | (ub & 0xffff0000u);
}
// exact residual after hi-truncation
__device__ __forceinline__ float trunc_lo(float x) {
    unsigned u = __builtin_bit_cast(unsigned, x) & 0xffff0000u;
    return x - __builtin_bit_cast(float, u);
}

__device__ __forceinline__ float gelu_f(float x) {
    // tanh-approx gelu == x * sigmoid(2t); 2t = 1.59577x + 0.0713549x^3
    float y = x * fmaf(0.0713549064f, x * x, 1.5957691216f);
    float e = __expf(y);                 // inf-safe: rcp(inf)=0 -> gelu=x
    return x - x * __builtin_amdgcn_rcpf(e + 1.0f);
}

// ---------------- K0: pack pair-MLP weights into MFMA A-fragments (hi/lo bf16) ----------------
__global__ __launch_bounds__(256) void k_prep(
    const float* __restrict__ w0, const float* __restrict__ w1,
    const float* __restrict__ w2, const float* __restrict__ w3,
    unsigned short* __restrict__ wp) {
    int t = threadIdx.x;
    // layer0 k-slot packing: A slots 0-3 = Wh, 4-7 = Wh (pairs with Fl), 8-11 = Wl, 12-31 = 0
    for (int e = t; e < 2048; e += 256) {
        int fi = e >> 3, j = e & 7;
        int mt = fi >> 6, lane = fi & 63;
        int q = lane >> 4, ln = lane & 15;
        int s = q * 8 + j;
        int m = mt * 16 + ln;
        unsigned short v = 0;
        if (s < 4) v = bf16h(w0[s * 64 + m]);
        else if (s < 8) v = bf16h(w0[(s - 4) * 64 + m]);
        else if (s < 12) {
            float x = w0[(s - 8) * 64 + m];
            v = bf16h(x - bf16tof(bf16h(x)));
        }
        wp[UA0 + e] = v;
    }
    // layers 1,2: A[m=out][k=in] frags, frag fi=(mt*2+ks)*64+lane, elem j -> k=ks*32+(lane>>4)*8+j
    for (int e = t; e < 4096; e += 256) {
        int fi = e >> 3, j = e & 7;
        int mt = fi >> 7, ks = (fi >> 6) & 1, lane = fi & 63;
        int k = ks * 32 + ((lane >> 4) << 3) + j;
        int m = mt * 16 + (lane & 15);
        float x1 = w1[k * 64 + m];
        unsigned short h1 = bf16h(x1);
        wp[UA1H + e] = h1;
        wp[UA1L + e] = bf16h(x1 - bf16tof(h1));
        float x2 = w2[k * 64 + m];
        unsigned short h2 = bf16h(x2);
        wp[UA2H + e] = h2;
        wp[UA2L + e] = bf16h(x2 - bf16tof(h2));
    }
    // layer3: single m-tile (rows 8..15 zero)
    for (int e = t; e < 1024; e += 256) {
        int fi = e >> 3, j = e & 7;
        int ks = fi >> 6, lane = fi & 63;
        int k = ks * 32 + ((lane >> 4) << 3) + j;
        int m = lane & 15;
        float x = (m < 8) ? w3[k * 8 + m] : 0.0f;
        unsigned short h = bf16h(x);
        wp[UA3H + e] = h;
        wp[UA3L + e] = bf16h(x - bf16tof(h));
    }
}

// ---------------- K1: per-particle features ----------------
__global__ __launch_bounds__(256) void k_particle(const float* __restrict__ x_pf,
                                                  float* __restrict__ ws) {
    int idx = blockIdx.x * 256 + threadIdx.x;      // 0 .. 4095
    int b = idx >> 8, n = idx & 255;
    const float* base = x_pf + (size_t)b * 4 * N_;
    float px = base[0 * N_ + n];
    float py = base[1 * N_ + n];
    float pz = base[2 * N_ + n];
    float e  = base[3 * N_ + n];
    float pt  = sqrtf(fmaxf(px * px + py * py, EPS_));
    float rap = 0.5f * log1pf(2.0f * pz / fmaxf(e - pz, 1e-20f));
    float phi = atan2f(py, px);
    ws[OFF_PT  + idx] = pt;
    ws[OFF_RAP + idx] = rap;
    ws[OFF_PHI + idx] = phi;
    ws[OFF_PX  + idx] = px;
    ws[OFF_PY  + idx] = py;
    ws[OFF_PZ  + idx] = pz;
    ws[OFF_E   + idx] = e;
}

// epilogue: bias + gelu on acc (C-layout), then shuffle-transpose into next-layer B-frags.
// C-layout: value V[m][n], m = mt*16 + q*4 + r, n = nt*16 + ln.
// B-frag dest (ln,q,nt,ks,j): k = ks*32 + q*8 + j -> src lane (2*(q&1)+(j>>2))*16 + ln,
// tile mt = 2ks + (q>>1), reg r = j&3.
__device__ __forceinline__ void epi_transpose(f4 (&acc)[4][4], const float* __restrict__ bg,
                                              int ln, int q,
                                              s8 (&Bh)[4][2], s8 (&Bl)[4][2]) {
    unsigned ph01[4][4], ph23[4][4], pl01[4][4], pl23[4][4];
#pragma unroll
    for (int mt = 0; mt < 4; ++mt) {
        f4 bv = *(const f4*)&bg[mt * 16 + q * 4];
#pragma unroll
        for (int nt = 0; nt < 4; ++nt) {
            float g0 = gelu_f(acc[mt][nt][0] + bv[0]);
            float g1 = gelu_f(acc[mt][nt][1] + bv[1]);
            float g2 = gelu_f(acc[mt][nt][2] + bv[2]);
            float g3 = gelu_f(acc[mt][nt][3] + bv[3]);
            ph01[mt][nt] = pack_hi2(g0, g1);
            ph23[mt][nt] = pack_hi2(g2, g3);
            pl01[mt][nt] = pack_hi2(trunc_lo(g0), trunc_lo(g1));
            pl23[mt][nt] = pack_hi2(trunc_lo(g2), trunc_lo(g3));
        }
    }
    int srcA = (q & 1) * 32 + ln;
    int srcB = srcA + 16;
    bool sel = (q & 2) != 0;
#pragma unroll
    for (int nt = 0; nt < 4; ++nt) {
#pragma unroll
        for (int ks = 0; ks < 2; ++ks) {
            int m0 = 2 * ks, m1 = 2 * ks + 1;
            u4 hu, lu;
            unsigned a_, b_;
            a_ = (unsigned)__shfl((int)ph01[m0][nt], srcA); b_ = (unsigned)__shfl((int)ph01[m1][nt], srcA); hu[0] = sel ? b_ : a_;
            a_ = (unsigned)__shfl((int)ph23[m0][nt], srcA); b_ = (unsigned)__shfl((int)ph23[m1][nt], srcA); hu[1] = sel ? b_ : a_;
            a_ = (unsigned)__shfl((int)ph01[m0][nt], srcB); b_ = (unsigned)__shfl((int)ph01[m1][nt], srcB); hu[2] = sel ? b_ : a_;
            a_ = (unsigned)__shfl((int)ph23[m0][nt], srcB); b_ = (unsigned)__shfl((int)ph23[m1][nt], srcB); hu[3] = sel ? b_ : a_;
            a_ = (unsigned)__shfl((int)pl01[m0][nt], srcA); b_ = (unsigned)__shfl((int)pl01[m1][nt], srcA); lu[0] = sel ? b_ : a_;
            a_ = (unsigned)__shfl((int)pl23[m0][nt], srcA); b_ = (unsigned)__shfl((int)pl23[m1][nt], srcA); lu[1] = sel ? b_ : a_;
            a_ = (unsigned)__shfl((int)pl01[m0][nt], srcB); b_ = (unsigned)__shfl((int)pl01[m1][nt], srcB); lu[2] = sel ? b_ : a_;
            a_ = (unsigned)__shfl((int)pl23[m0][nt], srcB); b_ = (unsigned)__shfl((int)pl23[m1][nt], srcB); lu[3] = sel ? b_ : a_;
            Bh[nt][ks] = __builtin_bit_cast(s8, hu);
            Bl[nt][ks] = __builtin_bit_cast(s8, lu);
        }
    }
}

__device__ __forceinline__ void mid_layer(f4 (&acc)[4][4],
                                          const unsigned short* __restrict__ wh,
                                          const unsigned short* __restrict__ wl,
                                          int lane, s8 (&Bh)[4][2], s8 (&Bl)[4][2]) {
    const f4 zero4 = { 0.f, 0.f, 0.f, 0.f };
#pragma unroll
    for (int mt = 0; mt < 4; ++mt) {
        s8 ah0 = *(const s8*)&wh[((mt * 2 + 0) * 64 + lane) * 8];
        s8 ah1 = *(const s8*)&wh[((mt * 2 + 1) * 64 + lane) * 8];
        s8 al0 = *(const s8*)&wl[((mt * 2 + 0) * 64 + lane) * 8];
        s8 al1 = *(const s8*)&wl[((mt * 2 + 1) * 64 + lane) * 8];
#pragma unroll
        for (int nt = 0; nt < 4; ++nt) {
            f4 c = zero4;
            c = __builtin_amdgcn_mfma_f32_16x16x32_bf16(ah0, Bh[nt][0], c, 0, 0, 0);
            c = __builtin_amdgcn_mfma_f32_16x16x32_bf16(ah0, Bl[nt][0], c, 0, 0, 0);
            c = __builtin_amdgcn_mfma_f32_16x16x32_bf16(al0, Bh[nt][0], c, 0, 0, 0);
            c = __builtin_amdgcn_mfma_f32_16x16x32_bf16(ah1, Bh[nt][1], c, 0, 0, 0);
            c = __builtin_amdgcn_mfma_f32_16x16x32_bf16(ah1, Bl[nt][1], c, 0, 0, 0);
            c = __builtin_amdgcn_mfma_f32_16x16x32_bf16(al1, Bh[nt][1], c, 0, 0, 0);
            acc[mt][nt] = c;
        }
    }
}

// ---------------- K2: pairwise features + split-bf16 MFMA MLP (LDS-free, wave-local) ----------
// grid: 4096 blocks x 256 threads = 16384 independent waves; wave -> (row, 64-col slice)
__global__ __launch_bounds__(256, 3) void k_pair_mlp(
    const float* __restrict__ ws, const unsigned short* __restrict__ wp,
    const float* __restrict__ b0g, const float* __restrict__ b1g,
    const float* __restrict__ b2g, const float* __restrict__ b3g,
    float* __restrict__ bias_out) {
    int tid = threadIdx.x;
    int lane = tid & 63;
    int ln = lane & 15, q = lane >> 4;
    int wid = blockIdx.x * 4 + (tid >> 6);
    int row = wid >> 2;                     // b*N + i
    int j0 = (wid & 3) * 64;
    int b = row >> 8, i = row & 255;

    // ---- features for pair (i, j0+lane), packed hi/lo bf16 pairs ----
    unsigned FH01, FH23, FL01, FL23;
    {
        int ib = row;
        int jb = (b << 8) + j0 + lane;
        float pt_i = ws[OFF_PT + ib],  rap_i = ws[OFF_RAP + ib], phi_i = ws[OFF_PHI + ib];
        float px_i = ws[OFF_PX + ib],  py_i  = ws[OFF_PY  + ib];
        float pz_i = ws[OFF_PZ + ib],  e_i   = ws[OFF_E   + ib];
        float pt_j = ws[OFF_PT + jb],  rap_j = ws[OFF_RAP + jb], phi_j = ws[OFF_PHI + jb];
        float px_j = ws[OFF_PX + jb],  py_j  = ws[OFF_PY  + jb];
        float pz_j = ws[OFF_PZ + jb],  e_j   = ws[OFF_E   + jb];

        float drap = rap_i - rap_j;
        float xw = phi_i - phi_j + PI_F;
        float mw = xw - TWO_PI_F * floorf(xw * INV_TWO_PI_F);
        float dphi = mw - PI_F;
        float delta = sqrtf(drap * drap + dphi * dphi);
        float f2 = __logf(fmaxf(delta, EPS_));                            // lndelta
        float ptmin = fminf(pt_i, pt_j);
        float f0 = __logf(fmaxf(ptmin * delta, EPS_));                    // lnkt
        float f1 = __logf(fmaxf(ptmin / fmaxf(pt_i + pt_j, EPS_), EPS_)); // lnz
        float es = e_i + e_j, pxs = px_i + px_j, pys = py_i + py_j, pzs = pz_i + pz_j;
        float f3 = __logf(fmaxf(es * es - pxs * pxs - pys * pys - pzs * pzs, EPS_)); // lnm2

        FH01 = pack_hi2(f0, f1);
        FH23 = pack_hi2(f2, f3);
        FL01 = pack_hi2(trunc_lo(f0), trunc_lo(f1));
        FL23 = pack_hi2(trunc_lo(f2), trunc_lo(f3));
    }

    f4 acc[4][4];
    const f4 zero4 = { 0.f, 0.f, 0.f, 0.f };
#pragma unroll
    for (int mt = 0; mt < 4; ++mt)
#pragma unroll
        for (int nt = 0; nt < 4; ++nt) acc[mt][nt] = zero4;

    // ---- layer 0: 4 -> 64, B-frag built by shuffle from per-lane features ----
    {
        s8 a0[4];
#pragma unroll
        for (int mt = 0; mt < 4; ++mt)
            a0[mt] = *(const s8*)&wp[UA0 + (mt * 64 + lane) * 8];
#pragma unroll
        for (int nt = 0; nt < 4; ++nt) {
            int src = nt * 16 + ln;
            unsigned h01 = (unsigned)__shfl((int)FH01, src);
            unsigned h23 = (unsigned)__shfl((int)FH23, src);
            unsigned l01 = (unsigned)__shfl((int)FL01, src);
            unsigned l23 = (unsigned)__shfl((int)FL23, src);
            u4 bu;
            bu[0] = (q < 2) ? h01 : 0u;     // slots q*8..: q=0 -> Fh|Fl, q=1 -> Fh|0
            bu[1] = (q < 2) ? h23 : 0u;
            bu[2] = (q == 0) ? l01 : 0u;
            bu[3] = (q == 0) ? l23 : 0u;
            s8 bf = __builtin_bit_cast(s8, bu);
#pragma unroll
            for (int mt = 0; mt < 4; ++mt)
                acc[mt][nt] = __builtin_amdgcn_mfma_f32_16x16x32_bf16(a0[mt], bf, acc[mt][nt], 0, 0, 0);
        }
    }

    s8 Bh[4][2], Bl[4][2];
    epi_transpose(acc, b0g, ln, q, Bh, Bl);

    // ---- layer 1 ----
    mid_layer(acc, wp + UA1H, wp + UA1L, lane, Bh, Bl);
    epi_transpose(acc, b1g, ln, q, Bh, Bl);

    // ---- layer 2 ----
    mid_layer(acc, wp + UA2H, wp + UA2L, lane, Bh, Bl);
    epi_transpose(acc, b2g, ln, q, Bh, Bl);

    // ---- layer 3: 64 -> 8 ----
    {
        s8 a3h0 = *(const s8*)&wp[UA3H + (0 * 64 + lane) * 8];
        s8 a3h1 = *(const s8*)&wp[UA3H + (1 * 64 + lane) * 8];
        s8 a3l0 = *(const s8*)&wp[UA3L + (0 * 64 + lane) * 8];
        s8 a3l1 = *(const s8*)&wp[UA3L + (1 * 64 + lane) * 8];
        f4 acc3[4];
#pragma unroll
        for (int nt = 0; nt < 4; ++nt) {
            f4 c = zero4;
            c = __builtin_amdgcn_mfma_f32_16x16x32_bf16(a3h0, Bh[nt][0], c, 0, 0, 0);
            c = __builtin_amdgcn_mfma_f32_16x16x32_bf16(a3h0, Bl[nt][0], c, 0, 0, 0);
            c = __builtin_amdgcn_mfma_f32_16x16x32_bf16(a3l0, Bh[nt][0], c, 0, 0, 0);
            c = __builtin_amdgcn_mfma_f32_16x16x32_bf16(a3h1, Bh[nt][1], c, 0, 0, 0);
            c = __builtin_amdgcn_mfma_f32_16x16x32_bf16(a3h1, Bl[nt][1], c, 0, 0, 0);
            c = __builtin_amdgcn_mfma_f32_16x16x32_bf16(a3l1, Bh[nt][1], c, 0, 0, 0);
            acc3[nt] = c;
        }
        if (q < 2) {                       // rows 0-7 hold the H=8 outputs
            f4 b3v = *(const f4*)&b3g[q * 4];
#pragma unroll
            for (int nt = 0; nt < 4; ++nt) {
                int jc = j0 + nt * 16 + ln;
#pragma unroll
                for (int r = 0; r < 4; ++r) {
                    int out = q * 4 + r;
                    bias_out[(((size_t)(b * H_ + out)) * N_ + i) * N_ + jc] = acc3[nt][r] + b3v[r];
                }
            }
        }
    }
}

// ---------------- K3: QKV projection ----------------
__global__ __launch_bounds__(128) void k_qkv(
    const float* __restrict__ xf,
    const float* __restrict__ wq, const float* __restrict__ wk, const float* __restrict__ wv,
    const float* __restrict__ bq, const float* __restrict__ bk, const float* __restrict__ bv,
    float* __restrict__ ws) {
    __shared__ float lx[8 * 128];
    int o = threadIdx.x;
    int r0 = blockIdx.x * 8;                 // row = b*N+n
    for (int t = o; t < 1024; t += 128) lx[t] = xf[(size_t)r0 * 128 + t];
    __syncthreads();
    float aq[8], ak[8], av[8];
    float bqo = bq[o], bko = bk[o], bvo = bv[o];
#pragma unroll
    for (int r = 0; r < 8; ++r) { aq[r] = bqo; ak[r] = bko; av[r] = bvo; }
    for (int k = 0; k < 128; ++k) {
        float wqk = wq[k * 128 + o];
        float wkk = wk[k * 128 + o];
        float wvk = wv[k * 128 + o];
#pragma unroll
        for (int r = 0; r < 8; ++r) {
            float xv = lx[r * 128 + k];
            aq[r] = fmaf(xv, wqk, aq[r]);
            ak[r] = fmaf(xv, wkk, ak[r]);
            av[r] = fmaf(xv, wvk, av[r]);
        }
    }
#pragma unroll
    for (int r = 0; r < 8; ++r) {
        size_t off = ((size_t)(r0 + r)) * 128 + o;
        ws[OFF_Q + off] = aq[r];
        ws[OFF_K + off] = ak[r];
        ws[OFF_V + off] = av[r];
    }
}

// ---------------- K4: attention — block per (b,h,4i), K/V staged in LDS ----------------
#define KV_STRIDE 20   // dwords per row (pad 16 -> 20: conflict-free b128, 16B aligned)
__global__ __launch_bounds__(256) void k_attn(const float* __restrict__ ws,
                                              float* __restrict__ wso) {
    __shared__ __align__(16) float K_lds[256 * KV_STRIDE];
    __shared__ __align__(16) float V_lds[256 * KV_STRIDE];
    int tid = threadIdx.x;
    int blk = blockIdx.x;                 // 0..8191
    int b = blk >> 9;
    int h = (blk >> 6) & 7;
    int i0 = (blk & 63) << 2;

    const float* kbp = ws + OFF_K + (size_t)b * N_ * D_ + h * HD_;
    const float* vbp = ws + OFF_V + (size_t)b * N_ * D_ + h * HD_;
    for (int idx = tid; idx < 1024; idx += 256) {
        int r = idx >> 2, f = idx & 3;
        float4 kv = *(const float4*)(kbp + (size_t)r * D_ + f * 4);
        float4 vv = *(const float4*)(vbp + (size_t)r * D_ + f * 4);
        *(float4*)&K_lds[r * KV_STRIDE + f * 4] = kv;
        *(float4*)&V_lds[r * KV_STRIDE + f * 4] = vv;
    }
    __syncthreads();

    int lane = tid & 63;
    int i = i0 + (tid >> 6);

    const float4* q4 = reinterpret_cast<const float4*>(ws + OFF_Q + ((size_t)(b * N_ + i)) * D_ + h * HD_);
    float4 qa = q4[0], qb = q4[1], qc = q4[2], qd = q4[3];
    const float* brow = ws + OFF_BIAS + (((size_t)(b * H_ + h)) * N_ + i) * N_;

    float s[4];
#pragma unroll
    for (int t = 0; t < 4; ++t) {
        int j = lane + 64 * t;
        const float4* k4 = (const float4*)&K_lds[j * KV_STRIDE];
        float4 ka = k4[0], kb = k4[1], kc = k4[2], kd = k4[3];
        float dot;
        dot = qa.x * ka.x;
        dot = fmaf(qa.y, ka.y, dot); dot = fmaf(qa.z, ka.z, dot); dot = fmaf(qa.w, ka.w, dot);
        dot = fmaf(qb.x, kb.x, dot); dot = fmaf(qb.y, kb.y, dot);
        dot = fmaf(qb.z, kb.z, dot); dot = fmaf(qb.w, kb.w, dot);
        dot = fmaf(qc.x, kc.x, dot); dot = fmaf(qc.y, kc.y, dot);
        dot = fmaf(qc.z, kc.z, dot); dot = fmaf(qc.w, kc.w, dot);
        dot = fmaf(qd.x, kd.x, dot); dot = fmaf(qd.y, kd.y, dot);
        dot = fmaf(qd.z, kd.z, dot); dot = fmaf(qd.w, kd.w, dot);
        s[t] = fmaf(0.25f, dot, brow[j]);
    }
    float mx = fmaxf(fmaxf(s[0], s[1]), fmaxf(s[2], s[3]));
#pragma unroll
    for (int off = 32; off; off >>= 1) mx = fmaxf(mx, __shfl_xor(mx, off));
    float p[4], l = 0.0f;
#pragma unroll
    for (int t = 0; t < 4; ++t) { p[t] = __expf(s[t] - mx); l += p[t]; }
#pragma unroll
    for (int off = 32; off; off >>= 1) l += __shfl_xor(l, off);

    float acc[16];
#pragma unroll
    for (int d = 0; d < 16; ++d) acc[d] = 0.0f;
#pragma unroll
    for (int t = 0; t < 4; ++t) {
        int j = lane + 64 * t;
        const float4* v4 = (const float4*)&V_lds[j * KV_STRIDE];
        float4 va = v4[0], vb = v4[1], vc = v4[2], vd = v4[3];
        float pt = p[t];
        acc[0]  = fmaf(pt, va.x, acc[0]);  acc[1]  = fmaf(pt, va.y, acc[1]);
        acc[2]  = fmaf(pt, va.z, acc[2]);  acc[3]  = fmaf(pt, va.w, acc[3]);
        acc[4]  = fmaf(pt, vb.x, acc[4]);  acc[5]  = fmaf(pt, vb.y, acc[5]);
        acc[6]  = fmaf(pt, vb.z, acc[6]);  acc[7]  = fmaf(pt, vb.w, acc[7]);
        acc[8]  = fmaf(pt, vc.x, acc[8]);  acc[9]  = fmaf(pt, vc.y, acc[9]);
        acc[10] = fmaf(pt, vc.z, acc[10]); acc[11] = fmaf(pt, vc.w, acc[11]);
        acc[12] = fmaf(pt, vd.x, acc[12]); acc[13] = fmaf(pt, vd.y, acc[13]);
        acc[14] = fmaf(pt, vd.z, acc[14]); acc[15] = fmaf(pt, vd.w, acc[15]);
    }
#pragma unroll
    for (int d = 0; d < 16; ++d) {
#pragma unroll
        for (int off = 32; off; off >>= 1) acc[d] += __shfl_xor(acc[d], off);
    }
    if (lane == 0) {
        float invl = 1.0f / l;
        float* op = wso + OFF_AO + ((size_t)(b * N_ + i)) * D_ + h * HD_;
#pragma unroll
        for (int d = 0; d < 16; ++d) op[d] = acc[d] * invl;
    }
}

// ---------------- K5: output projection ----------------
__global__ __launch_bounds__(128) void k_out(const float* __restrict__ ws,
                                             const float* __restrict__ wo,
                                             const float* __restrict__ bo,
                                             float* __restrict__ out) {
    __shared__ float lx[8 * 128];
    int o = threadIdx.x;
    int r0 = blockIdx.x * 8;
    for (int t = o; t < 1024; t += 128) lx[t] = ws[OFF_AO + (size_t)r0 * 128 + t];
    __syncthreads();
    float acc[8];
    float boo = bo[o];
#pragma unroll
    for (int r = 0; r < 8; ++r) acc[r] = boo;
    for (int k = 0; k < 128; ++k) {
        float w = wo[k * 128 + o];
#pragma unroll
        for (int r = 0; r < 8; ++r) acc[r] = fmaf(lx[r * 128 + k], w, acc[r]);
    }
#pragma unroll
    for (int r = 0; r < 8; ++r) out[((size_t)(r0 + r)) * 128 + o] = acc[r];
}

extern "C" void kernel_launch(void* const* d_in, const int* in_sizes, int n_in,
                              void* d_out, int out_size, void* d_ws, size_t ws_size,
                              hipStream_t stream) {
    const float* x_pf   = (const float*)d_in[0];
    const float* x_feat = (const float*)d_in[1];
    const float* w0 = (const float*)d_in[2];
    const float* b0 = (const float*)d_in[3];
    const float* w1 = (const float*)d_in[4];
    const float* b1 = (const float*)d_in[5];
    const float* w2 = (const float*)d_in[6];
    const float* b2 = (const float*)d_in[7];
    const float* w3 = (const float*)d_in[8];
    const float* b3 = (const float*)d_in[9];
    const float* wq = (const float*)d_in[10];
    const float* wk = (const float*)d_in[11];
    const float* wv = (const float*)d_in[12];
    const float* wo = (const float*)d_in[13];
    const float* bq = (const float*)d_in[14];
    const float* bk = (const float*)d_in[15];
    const float* bv = (const float*)d_in[16];
    const float* bo = (const float*)d_in[17];
    float* ws  = (float*)d_ws;
    float* out = (float*)d_out;
    unsigned short* wpack = (unsigned short*)(ws + OFF_WPACK);

    hipLaunchKernelGGL(k_prep, dim3(1), dim3(256), 0, stream, w0, w1, w2, w3, wpack);
    hipLaunchKernelGGL(k_particle, dim3(16), dim3(256), 0, stream, x_pf, ws);
    hipLaunchKernelGGL(k_pair_mlp, dim3(4096), dim3(256), 0, stream,
                       ws, wpack, b0, b1, b2, b3, ws + OFF_BIAS);
    hipLaunchKernelGGL(k_qkv, dim3(512), dim3(128), 0, stream,
                       x_feat, wq, wk, wv, bq, bk, bv, ws);
    hipLaunchKernelGGL(k_attn, dim3(8192), dim3(256), 0, stream, ws, ws);
    hipLaunchKernelGGL(k_out, dim3(512), dim3(128), 0, stream, ws, wo, bo, out);
}

// Round 5
// 257.266 us; speedup vs baseline: 3.0196x; 1.1424x over previous
//
#include <hip/hip_runtime.h>
#include <hip/hip_bf16.h>
#include <math.h>

#define B_ 16
#define N_ 256
#define D_ 128
#define H_ 8
#define HD_ 16
#define EPS_ 1e-8f
#define PI_F 3.14159265358979323846f
#define TWO_PI_F 6.28318530717958647692f
#define INV_TWO_PI_F 0.15915494309189533577f

// ---------------- workspace layout (float units) ----------------
#define OFF_PT   0               // 4096
#define OFF_RAP  4096
#define OFF_PHI  8192
#define OFF_PX   12288
#define OFF_PY   16384
#define OFF_PZ   20480
#define OFF_E    24576
#define OFF_Q    28672           // 524288
#define OFF_K    (28672 + 524288)
#define OFF_V    (28672 + 2*524288)
#define OFF_BIAS (28672 + 3*524288)     // 8388608 floats (B,H,N,N)
#define OFF_AO   (OFF_BIAS + 8388608)   // 524288
#define OFF_WPACK (OFF_AO + 524288)     // packed f16 weight frags

// packed weight-frag offsets (f16 units, relative to wp)
#define UA0  0        // 2048 : layer0 combined hi/lo k-slot packing
#define UA1H 2048     // 4096
#define UA1L 6144     // 4096
#define UA2H 10240    // 4096
#define UA2L 14336    // 4096
#define UA3H 18432    // 1024
#define UA3L 19456    // 1024

typedef _Float16 f16x8 __attribute__((ext_vector_type(8)));
typedef _Float16 f16x2 __attribute__((ext_vector_type(2)));
typedef __attribute__((ext_vector_type(4))) float f4;
typedef __attribute__((ext_vector_type(4))) unsigned int u4;

__device__ __forceinline__ unsigned pkh2(float a, float b) {
    f16x2 v = { (_Float16)a, (_Float16)b };          // RNE conversions
    return __builtin_bit_cast(unsigned, v);
}
__device__ __forceinline__ float f16res(float x) {   // exact residual of RNE f16
    return x - (float)(_Float16)x;
}

__device__ __forceinline__ float gelu_f(float x) {
    // tanh-approx gelu == x * sigmoid(y); y = 1.59577x + 0.0713549x^3
    float y = x * fmaf(0.0713549064f, x * x, 1.5957691216f);
    float e = __expf(y);                 // inf-safe: rcp(inf)=0 -> gelu=x
    return x - x * __builtin_amdgcn_rcpf(e + 1.0f);
}

// kappa permutation: k-slot (ks,q,j) -> original in-dim (2*(j>>2)+ks)*16 + q*4 + (j&3)
// This makes the next-layer B-fragment a pure in-lane rearrangement of C-layout accs.

// ---------------- K0: pack pair-MLP weights into MFMA A-fragments (hi/lo f16) ----------------
__global__ __launch_bounds__(256) void k_prep(
    const float* __restrict__ w0, const float* __restrict__ w1,
    const float* __restrict__ w2, const float* __restrict__ w3,
    _Float16* __restrict__ wp) {
    int t = threadIdx.x;
    // layer0: A slots (q=0): j0-3 = Whi rows, j4-7 = Wlo rows; (q=1): j0-3 = Whi, j4-7 = 0
    for (int e = t; e < 2048; e += 256) {
        int fi = e >> 3, j = e & 7;
        int mt = fi >> 6, lane = fi & 63;
        int q = lane >> 4, ln = lane & 15;
        int m = mt * 16 + ln;
        _Float16 v = (_Float16)0.0f;
        if (q == 0) v = (j < 4) ? (_Float16)w0[j * 64 + m]
                                : (_Float16)f16res(w0[(j - 4) * 64 + m]);
        else if (q == 1) v = (j < 4) ? (_Float16)w0[j * 64 + m] : (_Float16)0.0f;
        wp[UA0 + e] = v;
    }
    // layers 1,2: frag fi = (mt*2+ks)*64 + lane; k-row kappa-permuted
    for (int e = t; e < 4096; e += 256) {
        int fi = e >> 3, j = e & 7;
        int mt = fi >> 7, ks = (fi >> 6) & 1, lane = fi & 63;
        int q = lane >> 4;
        int m = mt * 16 + (lane & 15);
        int k = (2 * (j >> 2) + ks) * 16 + q * 4 + (j & 3);   // kappa
        float x1 = w1[k * 64 + m];
        wp[UA1H + e] = (_Float16)x1;
        wp[UA1L + e] = (_Float16)f16res(x1);
        float x2 = w2[k * 64 + m];
        wp[UA2H + e] = (_Float16)x2;
        wp[UA2L + e] = (_Float16)f16res(x2);
    }
    // layer3: single padded m-tile (rows 8..15 zero), kappa-permuted k
    for (int e = t; e < 1024; e += 256) {
        int fi = e >> 3, j = e & 7;
        int ks = fi >> 6, lane = fi & 63;
        int q = lane >> 4;
        int m = lane & 15;
        int k = (2 * (j >> 2) + ks) * 16 + q * 4 + (j & 3);   // kappa
        float x = (m < 8) ? w3[k * 8 + m] : 0.0f;
        wp[UA3H + e] = (_Float16)x;
        wp[UA3L + e] = (_Float16)f16res(x);
    }
}

// ---------------- K1: per-particle features ----------------
__global__ __launch_bounds__(256) void k_particle(const float* __restrict__ x_pf,
                                                  float* __restrict__ ws) {
    int idx = blockIdx.x * 256 + threadIdx.x;      // 0 .. 4095
    int b = idx >> 8, n = idx & 255;
    const float* base = x_pf + (size_t)b * 4 * N_;
    float px = base[0 * N_ + n];
    float py = base[1 * N_ + n];
    float pz = base[2 * N_ + n];
    float e  = base[3 * N_ + n];
    float pt  = sqrtf(fmaxf(px * px + py * py, EPS_));
    float rap = 0.5f * log1pf(2.0f * pz / fmaxf(e - pz, 1e-20f));
    float phi = atan2f(py, px);
    ws[OFF_PT  + idx] = pt;
    ws[OFF_RAP + idx] = rap;
    ws[OFF_PHI + idx] = phi;
    ws[OFF_PX  + idx] = px;
    ws[OFF_PY  + idx] = py;
    ws[OFF_PZ  + idx] = pz;
    ws[OFF_E   + idx] = e;
}

// epilogue: bias + gelu on C-layout accs, pack straight into next-layer B-frags (in-lane!).
// B[nt][ks] dwords: {pk(g[ks][nt][0..1]), pk(g[ks][nt][2..3]), pk(g[ks+2][nt][0..1]), pk(g[ks+2][nt][2..3])}
__device__ __forceinline__ void epi_frag(const f4 (&acc)[4][4], const float* __restrict__ bg,
                                         int q, u4 (&Bu)[4][2]) {
#pragma unroll
    for (int mt = 0; mt < 4; ++mt) {
        f4 bv = *(const f4*)&bg[mt * 16 + q * 4];
        int ks = mt & 1, hi = (mt >> 1) * 2;
#pragma unroll
        for (int nt = 0; nt < 4; ++nt) {
            float g0 = gelu_f(acc[mt][nt][0] + bv[0]);
            float g1 = gelu_f(acc[mt][nt][1] + bv[1]);
            float g2 = gelu_f(acc[mt][nt][2] + bv[2]);
            float g3 = gelu_f(acc[mt][nt][3] + bv[3]);
            Bu[nt][ks][hi]     = pkh2(g0, g1);
            Bu[nt][ks][hi + 1] = pkh2(g2, g3);
        }
    }
}

__device__ __forceinline__ void mid_layer(f4 (&acc)[4][4],
                                          const _Float16* __restrict__ wh,
                                          const _Float16* __restrict__ wl,
                                          int lane, const u4 (&Bu)[4][2]) {
    const f4 zero4 = { 0.f, 0.f, 0.f, 0.f };
#pragma unroll
    for (int mt = 0; mt < 4; ++mt) {
        f16x8 ah0 = *(const f16x8*)&wh[((mt * 2 + 0) * 64 + lane) * 8];
        f16x8 ah1 = *(const f16x8*)&wh[((mt * 2 + 1) * 64 + lane) * 8];
        f16x8 al0 = *(const f16x8*)&wl[((mt * 2 + 0) * 64 + lane) * 8];
        f16x8 al1 = *(const f16x8*)&wl[((mt * 2 + 1) * 64 + lane) * 8];
#pragma unroll
        for (int nt = 0; nt < 4; ++nt) {
            f16x8 b0 = __builtin_bit_cast(f16x8, Bu[nt][0]);
            f16x8 b1 = __builtin_bit_cast(f16x8, Bu[nt][1]);
            f4 c = zero4;
            c = __builtin_amdgcn_mfma_f32_16x16x32_f16(ah0, b0, c, 0, 0, 0);
            c = __builtin_amdgcn_mfma_f32_16x16x32_f16(al0, b0, c, 0, 0, 0);
            c = __builtin_amdgcn_mfma_f32_16x16x32_f16(ah1, b1, c, 0, 0, 0);
            c = __builtin_amdgcn_mfma_f32_16x16x32_f16(al1, b1, c, 0, 0, 0);
            acc[mt][nt] = c;
        }
    }
}

// ---------------- K2: pairwise features + f16 MFMA MLP (no LDS, no transposes) ----------
// grid: 4096 blocks x 256 threads = 16384 waves; wave -> (row, 64-col slice)
__global__ __launch_bounds__(256, 3) void k_pair_mlp(
    const float* __restrict__ ws, const _Float16* __restrict__ wp,
    const float* __restrict__ b0g, const float* __restrict__ b1g,
    const float* __restrict__ b2g, const float* __restrict__ b3g,
    float* __restrict__ bias_out) {
    int tid = threadIdx.x;
    int lane = tid & 63;
    int ln = lane & 15, q = lane >> 4;
    int wid = blockIdx.x * 4 + (tid >> 6);
    int row = wid >> 2;                     // b*N + i
    int j0 = (wid & 3) * 64;
    int b = row >> 8, i = row & 255;

    // ---- features for pair (i, j0+lane), hi/lo f16 pairs ----
    unsigned FH01, FH23, FL01, FL23;
    {
        int ib = row;
        int jb = (b << 8) + j0 + lane;
        float pt_i = ws[OFF_PT + ib],  rap_i = ws[OFF_RAP + ib], phi_i = ws[OFF_PHI + ib];
        float px_i = ws[OFF_PX + ib],  py_i  = ws[OFF_PY  + ib];
        float pz_i = ws[OFF_PZ + ib],  e_i   = ws[OFF_E   + ib];
        float pt_j = ws[OFF_PT + jb],  rap_j = ws[OFF_RAP + jb], phi_j = ws[OFF_PHI + jb];
        float px_j = ws[OFF_PX + jb],  py_j  = ws[OFF_PY  + jb];
        float pz_j = ws[OFF_PZ + jb],  e_j   = ws[OFF_E   + jb];

        float drap = rap_i - rap_j;
        float xw = phi_i - phi_j + PI_F;
        float mw = xw - TWO_PI_F * floorf(xw * INV_TWO_PI_F);
        float dphi = mw - PI_F;
        float delta = sqrtf(drap * drap + dphi * dphi);
        float f2 = __logf(fmaxf(delta, EPS_));                            // lndelta
        float ptmin = fminf(pt_i, pt_j);
        float f0 = __logf(fmaxf(ptmin * delta, EPS_));                    // lnkt
        float f1 = __logf(fmaxf(ptmin / fmaxf(pt_i + pt_j, EPS_), EPS_)); // lnz
        float es = e_i + e_j, pxs = px_i + px_j, pys = py_i + py_j, pzs = pz_i + pz_j;
        float f3 = __logf(fmaxf(es * es - pxs * pxs - pys * pys - pzs * pzs, EPS_)); // lnm2

        FH01 = pkh2(f0, f1);
        FH23 = pkh2(f2, f3);
        FL01 = pkh2(f16res(f0), f16res(f1));
        FL23 = pkh2(f16res(f2), f16res(f3));
    }

    f4 acc[4][4];
    const f4 zero4 = { 0.f, 0.f, 0.f, 0.f };

    // ---- layer 0: 4 -> 64, one MFMA per tile (Wh*Fh + Wl*Fh + Wh*Fl in k-slots) ----
    {
        f16x8 a0[4];
#pragma unroll
        for (int mt = 0; mt < 4; ++mt)
            a0[mt] = *(const f16x8*)&wp[UA0 + (mt * 64 + lane) * 8];
#pragma unroll
        for (int nt = 0; nt < 4; ++nt) {
            int src = nt * 16 + ln;
            unsigned h01 = (unsigned)__shfl((int)FH01, src);
            unsigned h23 = (unsigned)__shfl((int)FH23, src);
            unsigned l01 = (unsigned)__shfl((int)FL01, src);
            unsigned l23 = (unsigned)__shfl((int)FL23, src);
            u4 bu;
            bu[0] = (q == 0) ? h01 : ((q == 1) ? l01 : 0u);
            bu[1] = (q == 0) ? h23 : ((q == 1) ? l23 : 0u);
            bu[2] = (q == 0) ? h01 : 0u;
            bu[3] = (q == 0) ? h23 : 0u;
            f16x8 bf = __builtin_bit_cast(f16x8, bu);
#pragma unroll
            for (int mt = 0; mt < 4; ++mt)
                acc[mt][nt] = __builtin_amdgcn_mfma_f32_16x16x32_f16(a0[mt], bf, zero4, 0, 0, 0);
        }
    }

    u4 Bu[4][2];
    epi_frag(acc, b0g, q, Bu);

    // ---- layer 1 ----
    mid_layer(acc, wp + UA1H, wp + UA1L, lane, Bu);
    epi_frag(acc, b1g, q, Bu);

    // ---- layer 2 ----
    mid_layer(acc, wp + UA2H, wp + UA2L, lane, Bu);
    epi_frag(acc, b2g, q, Bu);

    // ---- layer 3: 64 -> 8 ----
    {
        f16x8 a3h0 = *(const f16x8*)&wp[UA3H + (0 * 64 + lane) * 8];
        f16x8 a3h1 = *(const f16x8*)&wp[UA3H + (1 * 64 + lane) * 8];
        f16x8 a3l0 = *(const f16x8*)&wp[UA3L + (0 * 64 + lane) * 8];
        f16x8 a3l1 = *(const f16x8*)&wp[UA3L + (1 * 64 + lane) * 8];
        f4 acc3[4];
#pragma unroll
        for (int nt = 0; nt < 4; ++nt) {
            f16x8 b0 = __builtin_bit_cast(f16x8, Bu[nt][0]);
            f16x8 b1 = __builtin_bit_cast(f16x8, Bu[nt][1]);
            f4 c = zero4;
            c = __builtin_amdgcn_mfma_f32_16x16x32_f16(a3h0, b0, c, 0, 0, 0);
            c = __builtin_amdgcn_mfma_f32_16x16x32_f16(a3l0, b0, c, 0, 0, 0);
            c = __builtin_amdgcn_mfma_f32_16x16x32_f16(a3h1, b1, c, 0, 0, 0);
            c = __builtin_amdgcn_mfma_f32_16x16x32_f16(a3l1, b1, c, 0, 0, 0);
            acc3[nt] = c;
        }
        if (q < 2) {                       // rows 0-7 hold the H=8 outputs
            f4 b3v = *(const f4*)&b3g[q * 4];
#pragma unroll
            for (int nt = 0; nt < 4; ++nt) {
                int jc = j0 + nt * 16 + ln;
#pragma unroll
                for (int r = 0; r < 4; ++r) {
                    int out = q * 4 + r;
                    bias_out[(((size_t)(b * H_ + out)) * N_ + i) * N_ + jc] = acc3[nt][r] + b3v[r];
                }
            }
        }
    }
}

// ---------------- K3: QKV projection ----------------
__global__ __launch_bounds__(128) void k_qkv(
    const float* __restrict__ xf,
    const float* __restrict__ wq, const float* __restrict__ wk, const float* __restrict__ wv,
    const float* __restrict__ bq, const float* __restrict__ bk, const float* __restrict__ bv,
    float* __restrict__ ws) {
    __shared__ float lx[8 * 128];
    int o = threadIdx.x;
    int r0 = blockIdx.x * 8;                 // row = b*N+n
    for (int t = o; t < 1024; t += 128) lx[t] = xf[(size_t)r0 * 128 + t];
    __syncthreads();
    float aq[8], ak[8], av[8];
    float bqo = bq[o], bko = bk[o], bvo = bv[o];
#pragma unroll
    for (int r = 0; r < 8; ++r) { aq[r] = bqo; ak[r] = bko; av[r] = bvo; }
    for (int k = 0; k < 128; ++k) {
        float wqk = wq[k * 128 + o];
        float wkk = wk[k * 128 + o];
        float wvk = wv[k * 128 + o];
#pragma unroll
        for (int r = 0; r < 8; ++r) {
            float xv = lx[r * 128 + k];
            aq[r] = fmaf(xv, wqk, aq[r]);
            ak[r] = fmaf(xv, wkk, ak[r]);
            av[r] = fmaf(xv, wvk, av[r]);
        }
    }
#pragma unroll
    for (int r = 0; r < 8; ++r) {
        size_t off = ((size_t)(r0 + r)) * 128 + o;
        ws[OFF_Q + off] = aq[r];
        ws[OFF_K + off] = ak[r];
        ws[OFF_V + off] = av[r];
    }
}

// ---------------- K4: attention — block per (b,h,16i), 4 i per wave, K/V staged once ------
#define KV_STRIDE 20   // dwords per row (pad 16 -> 20: conflict-free b128, 16B aligned)
__global__ __launch_bounds__(256) void k_attn(const float* __restrict__ ws,
                                              float* __restrict__ wso) {
    __shared__ __align__(16) float K_lds[256 * KV_STRIDE];
    __shared__ __align__(16) float V_lds[256 * KV_STRIDE];
    int tid = threadIdx.x;
    int blk = blockIdx.x;                 // 0..2047
    int b = blk >> 7;
    int h = (blk >> 4) & 7;
    int i0 = (blk & 15) << 4;

    const float* kbp = ws + OFF_K + (size_t)b * N_ * D_ + h * HD_;
    const float* vbp = ws + OFF_V + (size_t)b * N_ * D_ + h * HD_;
    for (int idx = tid; idx < 1024; idx += 256) {
        int r = idx >> 2, f = idx & 3;
        *(float4*)&K_lds[r * KV_STRIDE + f * 4] = *(const float4*)(kbp + (size_t)r * D_ + f * 4);
        *(float4*)&V_lds[r * KV_STRIDE + f * 4] = *(const float4*)(vbp + (size_t)r * D_ + f * 4);
    }
    __syncthreads();

    int lane = tid & 63;
    int ibase = i0 + (tid >> 6) * 4;

#pragma unroll 1
    for (int ii = 0; ii < 4; ++ii) {
        int i = ibase + ii;
        const float4* q4 = reinterpret_cast<const float4*>(ws + OFF_Q + ((size_t)(b * N_ + i)) * D_ + h * HD_);
        float4 qa = q4[0], qb = q4[1], qc = q4[2], qd = q4[3];
        const float* brow = ws + OFF_BIAS + (((size_t)(b * H_ + h)) * N_ + i) * N_;

        float s[4];
#pragma unroll
        for (int t = 0; t < 4; ++t) {
            int j = lane + 64 * t;
            const float4* k4 = (const float4*)&K_lds[j * KV_STRIDE];
            float4 ka = k4[0], kb = k4[1], kc = k4[2], kd = k4[3];
            float dot;
            dot = qa.x * ka.x;
            dot = fmaf(qa.y, ka.y, dot); dot = fmaf(qa.z, ka.z, dot); dot = fmaf(qa.w, ka.w, dot);
            dot = fmaf(qb.x, kb.x, dot); dot = fmaf(qb.y, kb.y, dot);
            dot = fmaf(qb.z, kb.z, dot); dot = fmaf(qb.w, kb.w, dot);
            dot = fmaf(qc.x, kc.x, dot); dot = fmaf(qc.y, kc.y, dot);
            dot = fmaf(qc.z, kc.z, dot); dot = fmaf(qc.w, kc.w, dot);
            dot = fmaf(qd.x, kd.x, dot); dot = fmaf(qd.y, kd.y, dot);
            dot = fmaf(qd.z, kd.z, dot); dot = fmaf(qd.w, kd.w, dot);
            s[t] = fmaf(0.25f, dot, brow[j]);
        }
        float mx = fmaxf(fmaxf(s[0], s[1]), fmaxf(s[2], s[3]));
#pragma unroll
        for (int off = 32; off; off >>= 1) mx = fmaxf(mx, __shfl_xor(mx, off));
        float p[4], l = 0.0f;
#pragma unroll
        for (int t = 0; t < 4; ++t) { p[t] = __expf(s[t] - mx); l += p[t]; }
#pragma unroll
        for (int off = 32; off; off >>= 1) l += __shfl_xor(l, off);

        float acc[16];
#pragma unroll
        for (int d = 0; d < 16; ++d) acc[d] = 0.0f;
#pragma unroll
        for (int t = 0; t < 4; ++t) {
            int j = lane + 64 * t;
            const float4* v4 = (const float4*)&V_lds[j * KV_STRIDE];
            float4 va = v4[0], vb = v4[1], vc = v4[2], vd = v4[3];
            float pt = p[t];
            acc[0]  = fmaf(pt, va.x, acc[0]);  acc[1]  = fmaf(pt, va.y, acc[1]);
            acc[2]  = fmaf(pt, va.z, acc[2]);  acc[3]  = fmaf(pt, va.w, acc[3]);
            acc[4]  = fmaf(pt, vb.x, acc[4]);  acc[5]  = fmaf(pt, vb.y, acc[5]);
            acc[6]  = fmaf(pt, vb.z, acc[6]);  acc[7]  = fmaf(pt, vb.w, acc[7]);
            acc[8]  = fmaf(pt, vc.x, acc[8]);  acc[9]  = fmaf(pt, vc.y, acc[9]);
            acc[10] = fmaf(pt, vc.z, acc[10]); acc[11] = fmaf(pt, vc.w, acc[11]);
            acc[12] = fmaf(pt, vd.x, acc[12]); acc[13] = fmaf(pt, vd.y, acc[13]);
            acc[14] = fmaf(pt, vd.z, acc[14]); acc[15] = fmaf(pt, vd.w, acc[15]);
        }
#pragma unroll
        for (int d = 0; d < 16; ++d) {
#pragma unroll
            for (int off = 32; off; off >>= 1) acc[d] += __shfl_xor(acc[d], off);
        }
        if (lane == 0) {
            float invl = 1.0f / l;
            float* op = wso + OFF_AO + ((size_t)(b * N_ + i)) * D_ + h * HD_;
#pragma unroll
            for (int d = 0; d < 16; ++d) op[d] = acc[d] * invl;
        }
    }
}

// ---------------- K5: output projection ----------------
__global__ __launch_bounds__(128) void k_out(const float* __restrict__ ws,
                                             const float* __restrict__ wo,
                                             const float* __restrict__ bo,
                                             float* __restrict__ out) {
    __shared__ float lx[8 * 128];
    int o = threadIdx.x;
    int r0 = blockIdx.x * 8;
    for (int t = o; t < 1024; t += 128) lx[t] = ws[OFF_AO + (size_t)r0 * 128 + t];
    __syncthreads();
    float acc[8];
    float boo = bo[o];
#pragma unroll
    for (int r = 0; r < 8; ++r) acc[r] = boo;
    for (int k = 0; k < 128; ++k) {
        float w = wo[k * 128 + o];
#pragma unroll
        for (int r = 0; r < 8; ++r) acc[r] = fmaf(lx[r * 128 + k], w, acc[r]);
    }
#pragma unroll
    for (int r = 0; r < 8; ++r) out[((size_t)(r0 + r)) * 128 + o] = acc[r];
}

extern "C" void kernel_launch(void* const* d_in, const int* in_sizes, int n_in,
                              void* d_out, int out_size, void* d_ws, size_t ws_size,
                              hipStream_t stream) {
    const float* x_pf   = (const float*)d_in[0];
    const float* x_feat = (const float*)d_in[1];
    const float* w0 = (const float*)d_in[2];
    const float* b0 = (const float*)d_in[3];
    const float* w1 = (const float*)d_in[4];
    const float* b1 = (const float*)d_in[5];
    const float* w2 = (const float*)d_in[6];
    const float* b2 = (const float*)d_in[7];
    const float* w3 = (const float*)d_in[8];
    const float* b3 = (const float*)d_in[9];
    const float* wq = (const float*)d_in[10];
    const float* wk = (const float*)d_in[11];
    const float* wv = (const float*)d_in[12];
    const float* wo = (const float*)d_in[13];
    const float* bq = (const float*)d_in[14];
    const float* bk = (const float*)d_in[15];
    const float* bv = (const float*)d_in[16];
    const float* bo = (const float*)d_in[17];
    float* ws  = (float*)d_ws;
    float* out = (float*)d_out;
    _Float16* wpack = (_Float16*)(ws + OFF_WPACK);

    hipLaunchKernelGGL(k_prep, dim3(1), dim3(256), 0, stream, w0, w1, w2, w3, wpack);
    hipLaunchKernelGGL(k_particle, dim3(16), dim3(256), 0, stream, x_pf, ws);
    hipLaunchKernelGGL(k_pair_mlp, dim3(4096), dim3(256), 0, stream,
                       ws, wpack, b0, b1, b2, b3, ws + OFF_BIAS);
    hipLaunchKernelGGL(k_qkv, dim3(512), dim3(128), 0, stream,
                       x_feat, wq, wk, wv, bq, bk, bv, ws);
    hipLaunchKernelGGL(k_attn, dim3(2048), dim3(256), 0, stream, ws, ws);
    hipLaunchKernelGGL(k_out, dim3(512), dim3(128), 0, stream, ws, wo, bo, out);
}

// Round 6
// 195.980 us; speedup vs baseline: 3.9639x; 1.3127x over previous
//
#include <hip/hip_runtime.h>
#include <hip/hip_bf16.h>
#include <math.h>

#define B_ 16
#define N_ 256
#define D_ 128
#define H_ 8
#define HD_ 16
#define EPS_ 1e-8f
#define PI_F 3.14159265358979323846f
#define TWO_PI_F 6.28318530717958647692f
#define INV_TWO_PI_F 0.15915494309189533577f
#define L2E_F 1.4426950408889634f

// ---------------- workspace layout (float units) ----------------
#define OFF_PT   0               // 4096
#define OFF_RAP  4096
#define OFF_PHI  8192
#define OFF_PX   12288
#define OFF_PY   16384
#define OFF_PZ   20480
#define OFF_E    24576
#define OFF_Q    28672           // 524288
#define OFF_K    (28672 + 524288)
#define OFF_V    (28672 + 2*524288)
#define OFF_BIAS (28672 + 3*524288)     // 8388608 floats (B,H,N,N)
#define OFF_AO   (OFF_BIAS + 8388608)   // 524288
#define OFF_WPACK (OFF_AO + 524288)     // packed f16 weight frags

// packed weight-frag offsets (f16 units, relative to wp)
#define UA0  0        // 2048 : layer0 combined hi/lo k-slot packing
#define UA1H 2048     // 4096
#define UA1L 6144     // 4096
#define UA2H 10240    // 4096
#define UA2L 14336    // 4096
#define UA3H 18432    // 1024
#define UA3L 19456    // 1024
#define UQKV 20480    // 4 matrices (wq,wk,wv,wo): each hi 16384 + lo 16384
// total 20480 + 131072 = 151552 f16

typedef _Float16 f16x8 __attribute__((ext_vector_type(8)));
typedef _Float16 f16x4 __attribute__((ext_vector_type(4)));
typedef _Float16 f16x2 __attribute__((ext_vector_type(2)));
typedef __attribute__((ext_vector_type(4))) float f4;
typedef __attribute__((ext_vector_type(4))) unsigned int u4;

__device__ __forceinline__ unsigned pkh2(float a, float b) {
    f16x2 v = { (_Float16)a, (_Float16)b };          // RNE conversions
    return __builtin_bit_cast(unsigned, v);
}
__device__ __forceinline__ float f16res(float x) {   // exact residual of RNE f16
    return x - (float)(_Float16)x;
}

__device__ __forceinline__ float gelu_f(float x) {
    // tanh-approx gelu == x * sigmoid(y); y*log2e = 2.3022079x + 0.10294337x^3
    float y2 = x * fmaf(0.10294337f, x * x, 2.3022079f);
    float e = __builtin_amdgcn_exp2f(-y2);           // inf-safe both tails
    return x * __builtin_amdgcn_rcpf(1.0f + e);
}

// kappa permutation: k-slot (ks,q,j) <-> original index (2*(j>>2)+ks)*16 + q*4 + (j&3)

// ---------------- K0: pack all weights into MFMA A-fragments (hi/lo f16) ----------------
__global__ __launch_bounds__(256) void k_prep(
    const float* __restrict__ w0, const float* __restrict__ w1,
    const float* __restrict__ w2, const float* __restrict__ w3,
    const float* __restrict__ wq, const float* __restrict__ wk,
    const float* __restrict__ wv, const float* __restrict__ wo,
    _Float16* __restrict__ wp) {
    int id0 = blockIdx.x * 256 + threadIdx.x;
    int gs = gridDim.x * 256;
    // layer0: A slots (q=0): j0-3 = Whi rows, j4-7 = Wlo rows; (q=1): j0-3 = Whi, j4-7 = 0
    for (int e = id0; e < 2048; e += gs) {
        int fi = e >> 3, j = e & 7;
        int mt = fi >> 6, lane = fi & 63;
        int q = lane >> 4, ln = lane & 15;
        int m = mt * 16 + ln;
        _Float16 v = (_Float16)0.0f;
        if (q == 0) v = (j < 4) ? (_Float16)w0[j * 64 + m]
                                : (_Float16)f16res(w0[(j - 4) * 64 + m]);
        else if (q == 1) v = (j < 4) ? (_Float16)w0[j * 64 + m] : (_Float16)0.0f;
        wp[UA0 + e] = v;
    }
    // layers 1,2: frag fi = (mt*2+ks)*64 + lane; k-row kappa-permuted
    for (int e = id0; e < 4096; e += gs) {
        int fi = e >> 3, j = e & 7;
        int mt = fi >> 7, ks = (fi >> 6) & 1, lane = fi & 63;
        int q = lane >> 4;
        int m = mt * 16 + (lane & 15);
        int k = (2 * (j >> 2) + ks) * 16 + q * 4 + (j & 3);   // kappa
        float x1 = w1[k * 64 + m];
        wp[UA1H + e] = (_Float16)x1;
        wp[UA1L + e] = (_Float16)f16res(x1);
        float x2 = w2[k * 64 + m];
        wp[UA2H + e] = (_Float16)x2;
        wp[UA2L + e] = (_Float16)f16res(x2);
    }
    // layer3: single padded m-tile (rows 8..15 zero), kappa-permuted k
    for (int e = id0; e < 1024; e += gs) {
        int fi = e >> 3, j = e & 7;
        int ks = fi >> 6, lane = fi & 63;
        int q = lane >> 4;
        int m = lane & 15;
        int k = (2 * (j >> 2) + ks) * 16 + q * 4 + (j & 3);   // kappa
        float x = (m < 8) ? w3[k * 8 + m] : 0.0f;
        wp[UA3H + e] = (_Float16)x;
        wp[UA3L + e] = (_Float16)f16res(x);
    }
    // projection matrices: A[m=o][k=in], frag fi=(mt*4+ks)*64+lane (mt<8, ks<4)
    const float* mats[4] = { wq, wk, wv, wo };
#pragma unroll 1
    for (int mi = 0; mi < 4; ++mi) {
        const float* W = mats[mi];
        _Float16* dst = wp + UQKV + mi * 32768;
        for (int e = id0; e < 16384; e += gs) {
            int fi = e >> 3, j = e & 7;
            int mt = fi >> 8, ks = (fi >> 6) & 3, lane = fi & 63;
            int k = ks * 32 + ((lane >> 4) << 3) + j;
            int o = mt * 16 + (lane & 15);
            float x = W[k * 128 + o];
            dst[e] = (_Float16)x;
            dst[16384 + e] = (_Float16)f16res(x);
        }
    }
}

// ---------------- K1: per-particle features ----------------
__global__ __launch_bounds__(256) void k_particle(const float* __restrict__ x_pf,
                                                  float* __restrict__ ws) {
    int idx = blockIdx.x * 256 + threadIdx.x;      // 0 .. 4095
    int b = idx >> 8, n = idx & 255;
    const float* base = x_pf + (size_t)b * 4 * N_;
    float px = base[0 * N_ + n];
    float py = base[1 * N_ + n];
    float pz = base[2 * N_ + n];
    float e  = base[3 * N_ + n];
    float pt  = sqrtf(fmaxf(px * px + py * py, EPS_));
    float rap = 0.5f * log1pf(2.0f * pz / fmaxf(e - pz, 1e-20f));
    float phi = atan2f(py, px);
    ws[OFF_PT  + idx] = pt;
    ws[OFF_RAP + idx] = rap;
    ws[OFF_PHI + idx] = phi;
    ws[OFF_PX  + idx] = px;
    ws[OFF_PY  + idx] = py;
    ws[OFF_PZ  + idx] = pz;
    ws[OFF_E   + idx] = e;
}

// epilogue: bias + gelu on C-layout accs, pack straight into next-layer B-frags (in-lane).
__device__ __forceinline__ void epi_frag(const f4 (&acc)[4][4], const float* __restrict__ bg,
                                         int q, u4 (&Bu)[4][2]) {
#pragma unroll
    for (int mt = 0; mt < 4; ++mt) {
        f4 bv = *(const f4*)&bg[mt * 16 + q * 4];
        int ks = mt & 1, hi = (mt >> 1) * 2;
#pragma unroll
        for (int nt = 0; nt < 4; ++nt) {
            float g0 = gelu_f(acc[mt][nt][0] + bv[0]);
            float g1 = gelu_f(acc[mt][nt][1] + bv[1]);
            float g2 = gelu_f(acc[mt][nt][2] + bv[2]);
            float g3 = gelu_f(acc[mt][nt][3] + bv[3]);
            Bu[nt][ks][hi]     = pkh2(g0, g1);
            Bu[nt][ks][hi + 1] = pkh2(g2, g3);
        }
    }
}

__device__ __forceinline__ void mid_layer(f4 (&acc)[4][4],
                                          const _Float16* __restrict__ wh,
                                          const _Float16* __restrict__ wl,
                                          int lane, const u4 (&Bu)[4][2]) {
    const f4 zero4 = { 0.f, 0.f, 0.f, 0.f };
#pragma unroll
    for (int mt = 0; mt < 4; ++mt) {
        f16x8 ah0 = *(const f16x8*)&wh[((mt * 2 + 0) * 64 + lane) * 8];
        f16x8 ah1 = *(const f16x8*)&wh[((mt * 2 + 1) * 64 + lane) * 8];
        f16x8 al0 = *(const f16x8*)&wl[((mt * 2 + 0) * 64 + lane) * 8];
        f16x8 al1 = *(const f16x8*)&wl[((mt * 2 + 1) * 64 + lane) * 8];
#pragma unroll
        for (int nt = 0; nt < 4; ++nt) {
            f16x8 b0 = __builtin_bit_cast(f16x8, Bu[nt][0]);
            f16x8 b1 = __builtin_bit_cast(f16x8, Bu[nt][1]);
            f4 c = zero4;
            c = __builtin_amdgcn_mfma_f32_16x16x32_f16(ah0, b0, c, 0, 0, 0);
            c = __builtin_amdgcn_mfma_f32_16x16x32_f16(al0, b0, c, 0, 0, 0);
            c = __builtin_amdgcn_mfma_f32_16x16x32_f16(ah1, b1, c, 0, 0, 0);
            c = __builtin_amdgcn_mfma_f32_16x16x32_f16(al1, b1, c, 0, 0, 0);
            acc[mt][nt] = c;
        }
    }
}

// ---------------- K2: pairwise features + f16 MFMA MLP (no LDS, no transposes) ----------
__global__ __launch_bounds__(256, 4) void k_pair_mlp(
    const float* __restrict__ ws, const _Float16* __restrict__ wp,
    const float* __restrict__ b0g, const float* __restrict__ b1g,
    const float* __restrict__ b2g, const float* __restrict__ b3g,
    float* __restrict__ bias_out) {
    int tid = threadIdx.x;
    int lane = tid & 63;
    int ln = lane & 15, q = lane >> 4;
    int wid = blockIdx.x * 4 + (tid >> 6);
    int row = wid >> 2;                     // b*N + i
    int j0 = (wid & 3) * 64;
    int b = row >> 8, i = row & 255;

    unsigned FH01, FH23, FL01, FL23;
    {
        int ib = row;
        int jb = (b << 8) + j0 + lane;
        float pt_i = ws[OFF_PT + ib],  rap_i = ws[OFF_RAP + ib], phi_i = ws[OFF_PHI + ib];
        float px_i = ws[OFF_PX + ib],  py_i  = ws[OFF_PY  + ib];
        float pz_i = ws[OFF_PZ + ib],  e_i   = ws[OFF_E   + ib];
        float pt_j = ws[OFF_PT + jb],  rap_j = ws[OFF_RAP + jb], phi_j = ws[OFF_PHI + jb];
        float px_j = ws[OFF_PX + jb],  py_j  = ws[OFF_PY  + jb];
        float pz_j = ws[OFF_PZ + jb],  e_j   = ws[OFF_E   + jb];

        float drap = rap_i - rap_j;
        float xw = phi_i - phi_j + PI_F;
        float mw = xw - TWO_PI_F * floorf(xw * INV_TWO_PI_F);
        float dphi = mw - PI_F;
        float delta = sqrtf(drap * drap + dphi * dphi);
        float f2 = __logf(fmaxf(delta, EPS_));
        float ptmin = fminf(pt_i, pt_j);
        float f0 = __logf(fmaxf(ptmin * delta, EPS_));
        float f1 = __logf(fmaxf(ptmin / fmaxf(pt_i + pt_j, EPS_), EPS_));
        float es = e_i + e_j, pxs = px_i + px_j, pys = py_i + py_j, pzs = pz_i + pz_j;
        float f3 = __logf(fmaxf(es * es - pxs * pxs - pys * pys - pzs * pzs, EPS_));

        FH01 = pkh2(f0, f1);
        FH23 = pkh2(f2, f3);
        FL01 = pkh2(f16res(f0), f16res(f1));
        FL23 = pkh2(f16res(f2), f16res(f3));
    }

    f4 acc[4][4];
    const f4 zero4 = { 0.f, 0.f, 0.f, 0.f };

    // layer 0: 4 -> 64
    {
        f16x8 a0[4];
#pragma unroll
        for (int mt = 0; mt < 4; ++mt)
            a0[mt] = *(const f16x8*)&wp[UA0 + (mt * 64 + lane) * 8];
#pragma unroll
        for (int nt = 0; nt < 4; ++nt) {
            int src = nt * 16 + ln;
            unsigned h01 = (unsigned)__shfl((int)FH01, src);
            unsigned h23 = (unsigned)__shfl((int)FH23, src);
            unsigned l01 = (unsigned)__shfl((int)FL01, src);
            unsigned l23 = (unsigned)__shfl((int)FL23, src);
            u4 bu;
            bu[0] = (q == 0) ? h01 : ((q == 1) ? l01 : 0u);
            bu[1] = (q == 0) ? h23 : ((q == 1) ? l23 : 0u);
            bu[2] = (q == 0) ? h01 : 0u;
            bu[3] = (q == 0) ? h23 : 0u;
            f16x8 bf = __builtin_bit_cast(f16x8, bu);
#pragma unroll
            for (int mt = 0; mt < 4; ++mt)
                acc[mt][nt] = __builtin_amdgcn_mfma_f32_16x16x32_f16(a0[mt], bf, zero4, 0, 0, 0);
        }
    }

    u4 Bu[4][2];
    epi_frag(acc, b0g, q, Bu);
    mid_layer(acc, wp + UA1H, wp + UA1L, lane, Bu);
    epi_frag(acc, b1g, q, Bu);
    mid_layer(acc, wp + UA2H, wp + UA2L, lane, Bu);
    epi_frag(acc, b2g, q, Bu);

    // layer 3: 64 -> 8
    {
        f16x8 a3h0 = *(const f16x8*)&wp[UA3H + (0 * 64 + lane) * 8];
        f16x8 a3h1 = *(const f16x8*)&wp[UA3H + (1 * 64 + lane) * 8];
        f16x8 a3l0 = *(const f16x8*)&wp[UA3L + (0 * 64 + lane) * 8];
        f16x8 a3l1 = *(const f16x8*)&wp[UA3L + (1 * 64 + lane) * 8];
        f4 acc3[4];
#pragma unroll
        for (int nt = 0; nt < 4; ++nt) {
            f16x8 b0 = __builtin_bit_cast(f16x8, Bu[nt][0]);
            f16x8 b1 = __builtin_bit_cast(f16x8, Bu[nt][1]);
            f4 c = zero4;
            c = __builtin_amdgcn_mfma_f32_16x16x32_f16(a3h0, b0, c, 0, 0, 0);
            c = __builtin_amdgcn_mfma_f32_16x16x32_f16(a3l0, b0, c, 0, 0, 0);
            c = __builtin_amdgcn_mfma_f32_16x16x32_f16(a3h1, b1, c, 0, 0, 0);
            c = __builtin_amdgcn_mfma_f32_16x16x32_f16(a3l1, b1, c, 0, 0, 0);
            acc3[nt] = c;
        }
        if (q < 2) {
            f4 b3v = *(const f4*)&b3g[q * 4];
#pragma unroll
            for (int nt = 0; nt < 4; ++nt) {
                int jc = j0 + nt * 16 + ln;
#pragma unroll
                for (int r = 0; r < 4; ++r) {
                    int out = q * 4 + r;
                    bias_out[(((size_t)(b * H_ + out)) * N_ + i) * N_ + jc] = acc3[nt][r] + b3v[r];
                }
            }
        }
    }
}

// ---------------- shared 64-out x 16-token split-f16 MFMA GEMM tile ----------------
__device__ __forceinline__ void mfma_gemm64x16(
    const float* __restrict__ xrow,      // input row ptr for this lane's token (stride-128 matrix)
    const _Float16* __restrict__ wpm,    // A-frag pack (hi at +0, lo at +16384)
    int mtbase,                           // 0 or 4 (64-col group within 128)
    const float* __restrict__ biasv,     // bias + colbase
    float* __restrict__ outp,            // out + token*128 + colbase
    int lane) {
    int q = lane >> 4;
    const f4 zero4 = { 0.f, 0.f, 0.f, 0.f };
    f16x8 Bh[4], Bl[4];
#pragma unroll
    for (int ks = 0; ks < 4; ++ks) {
        const float* p = xrow + ks * 32 + q * 8;
        float4 xa = ((const float4*)p)[0];
        float4 xb = ((const float4*)p)[1];
        u4 hu = { pkh2(xa.x, xa.y), pkh2(xa.z, xa.w), pkh2(xb.x, xb.y), pkh2(xb.z, xb.w) };
        u4 lu = { pkh2(f16res(xa.x), f16res(xa.y)), pkh2(f16res(xa.z), f16res(xa.w)),
                  pkh2(f16res(xb.x), f16res(xb.y)), pkh2(f16res(xb.z), f16res(xb.w)) };
        Bh[ks] = __builtin_bit_cast(f16x8, hu);
        Bl[ks] = __builtin_bit_cast(f16x8, lu);
    }
#pragma unroll
    for (int mtl = 0; mtl < 4; ++mtl) {
        int mt = mtbase + mtl;
        f4 c = zero4;
#pragma unroll
        for (int ks = 0; ks < 4; ++ks) {
            const _Float16* fa = wpm + ((size_t)((mt * 4 + ks) * 64 + lane)) * 8;
            f16x8 ah = *(const f16x8*)fa;
            f16x8 al = *(const f16x8*)(fa + 16384);
            c = __builtin_amdgcn_mfma_f32_16x16x32_f16(ah, Bh[ks], c, 0, 0, 0);
            c = __builtin_amdgcn_mfma_f32_16x16x32_f16(ah, Bl[ks], c, 0, 0, 0);
            c = __builtin_amdgcn_mfma_f32_16x16x32_f16(al, Bh[ks], c, 0, 0, 0);
        }
        f4 bv = *(const f4*)&biasv[mtl * 16 + q * 4];
        f4 r = c + bv;
        *(f4*)(outp + mtl * 16 + q * 4) = r;
    }
}

// ---------------- K3: QKV projection (MFMA) — 384 blocks x 4 waves ----------------
__global__ __launch_bounds__(256) void k_qkv(
    const float* __restrict__ xf, const _Float16* __restrict__ wp,
    const float* __restrict__ bq, const float* __restrict__ bk, const float* __restrict__ bv,
    float* __restrict__ ws) {
    int tid = threadIdx.x;
    int lane = tid & 63, ln = lane & 15;
    int wid = blockIdx.x * 4 + (tid >> 6);       // 0..1535
    int og = wid % 6, tg = wid / 6;              // out-group (6x64), token-group (256x16)
    int mi = og >> 1, ch = og & 1;
    const _Float16* wpm = wp + UQKV + mi * 32768;
    const float* bias = (mi == 0) ? bq : ((mi == 1) ? bk : bv);
    float* outb = ws + OFF_Q + (size_t)mi * 524288;
    size_t tok = (size_t)(tg * 16 + ln);
    mfma_gemm64x16(xf + tok * 128, wpm, ch * 4, bias + ch * 64,
                   outb + tok * 128 + ch * 64, lane);
}

// ---------------- K4: attention (MFMA flash-row) — 512 blocks x 4 waves ----------------
#define SVT 264   // f16 stride of transposed V in LDS (264 = 4 mod 32 banks -> 2-way only)
__global__ __launch_bounds__(256) void k_attn(const float* __restrict__ ws,
                                              float* __restrict__ wso) {
    __shared__ __align__(16) _Float16 Vt[16 * SVT];
    int tid = threadIdx.x;
    int blk = blockIdx.x;                 // (b*8+h)*4 + ib
    int ib = blk & 3;
    int bh = blk >> 2;
    int b = bh >> 3, h = bh & 7;

    // stage V transposed: Vt[d][j] f16
    {
        const float* vr = ws + OFF_V + ((size_t)(b * 256 + tid)) * 128 + h * 16;
        float4 v0 = ((const float4*)vr)[0];
        float4 v1 = ((const float4*)vr)[1];
        float4 v2 = ((const float4*)vr)[2];
        float4 v3 = ((const float4*)vr)[3];
        Vt[ 0 * SVT + tid] = (_Float16)v0.x;  Vt[ 1 * SVT + tid] = (_Float16)v0.y;
        Vt[ 2 * SVT + tid] = (_Float16)v0.z;  Vt[ 3 * SVT + tid] = (_Float16)v0.w;
        Vt[ 4 * SVT + tid] = (_Float16)v1.x;  Vt[ 5 * SVT + tid] = (_Float16)v1.y;
        Vt[ 6 * SVT + tid] = (_Float16)v1.z;  Vt[ 7 * SVT + tid] = (_Float16)v1.w;
        Vt[ 8 * SVT + tid] = (_Float16)v2.x;  Vt[ 9 * SVT + tid] = (_Float16)v2.y;
        Vt[10 * SVT + tid] = (_Float16)v2.z;  Vt[11 * SVT + tid] = (_Float16)v2.w;
        Vt[12 * SVT + tid] = (_Float16)v3.x;  Vt[13 * SVT + tid] = (_Float16)v3.y;
        Vt[14 * SVT + tid] = (_Float16)v3.z;  Vt[15 * SVT + tid] = (_Float16)v3.w;
    }
    __syncthreads();

    int lane = tid & 63, w = tid >> 6;
    int ln = lane & 15, q = lane >> 4;
    int i0 = ib * 64 + w * 16;
    const f4 zero4 = { 0.f, 0.f, 0.f, 0.f };

    // B_Q: [Qh | Qh] across K=32 slots (d-half selected by q&1)
    f16x8 Bq;
    {
        const float* qr = ws + OFF_Q + ((size_t)(b * 256 + i0 + ln)) * 128 + h * 16 + (q & 1) * 8;
        float4 qa = ((const float4*)qr)[0];
        float4 qb = ((const float4*)qr)[1];
        u4 hu = { pkh2(qa.x, qa.y), pkh2(qa.z, qa.w), pkh2(qb.x, qb.y), pkh2(qb.z, qb.w) };
        Bq = __builtin_bit_cast(f16x8, hu);
    }

    // S^T = K · Q^T : A = [K_hi (q<2) | K_lo (q>=2)], 16 m-tiles over j
    f4 accs[16];
    const float* Kbase = ws + OFF_K + ((size_t)(b * 256)) * 128 + h * 16;
    const float* bb = ws + OFF_BIAS + ((size_t)(bh * 256 + i0 + ln)) * 256 + q * 4;
#pragma unroll
    for (int mt = 0; mt < 16; ++mt) {
        const float* kr = Kbase + (size_t)(mt * 16 + ln) * 128 + (q & 1) * 8;
        float4 ka = ((const float4*)kr)[0];
        float4 kb = ((const float4*)kr)[1];
        u4 hu = { pkh2(ka.x, ka.y), pkh2(ka.z, ka.w), pkh2(kb.x, kb.y), pkh2(kb.z, kb.w) };
        u4 lu = { pkh2(f16res(ka.x), f16res(ka.y)), pkh2(f16res(ka.z), f16res(ka.w)),
                  pkh2(f16res(kb.x), f16res(kb.y)), pkh2(f16res(kb.z), f16res(kb.w)) };
        u4 au;
        bool qlo = (q < 2);
        au[0] = qlo ? hu[0] : lu[0];
        au[1] = qlo ? hu[1] : lu[1];
        au[2] = qlo ? hu[2] : lu[2];
        au[3] = qlo ? hu[3] : lu[3];
        f16x8 Ak = __builtin_bit_cast(f16x8, au);
        f4 s = __builtin_amdgcn_mfma_f32_16x16x32_f16(Ak, Bq, zero4, 0, 0, 0);
        f4 bias4 = *(const f4*)&bb[mt * 16];
#pragma unroll
        for (int r = 0; r < 4; ++r) s[r] = fmaf(s[r], 0.25f, bias4[r]);
        accs[mt] = s;
    }

    // softmax over j (64 in-lane values + cross-q reduce; i = ln fixed per lane)
    float mx = accs[0][0];
#pragma unroll
    for (int mt = 0; mt < 16; ++mt)
#pragma unroll
        for (int r = 0; r < 4; ++r) mx = fmaxf(mx, accs[mt][r]);
    mx = fmaxf(mx, __shfl_xor(mx, 16));
    mx = fmaxf(mx, __shfl_xor(mx, 32));
    float nms = -mx * L2E_F;
    float l = 0.0f;
#pragma unroll
    for (int mt = 0; mt < 16; ++mt) {
#pragma unroll
        for (int r = 0; r < 4; ++r) {
            float p = __builtin_amdgcn_exp2f(fmaf(accs[mt][r], L2E_F, nms));
            accs[mt][r] = p;
            l += p;
        }
    }
    l += __shfl_xor(l, 16);
    l += __shfl_xor(l, 32);
    float inv = __builtin_amdgcn_rcpf(l);

    // O^T = V^T_perm · P^T  (kappa: in-lane P pack, permuted V read)
    f4 o = zero4;
#pragma unroll
    for (int ks = 0; ks < 8; ++ks) {
        u4 bp = { pkh2(accs[2 * ks][0], accs[2 * ks][1]),
                  pkh2(accs[2 * ks][2], accs[2 * ks][3]),
                  pkh2(accs[2 * ks + 1][0], accs[2 * ks + 1][1]),
                  pkh2(accs[2 * ks + 1][2], accs[2 * ks + 1][3]) };
        int vb = ln * SVT + 32 * ks + 4 * q;
        f16x4 lo4 = *(const f16x4*)&Vt[vb];
        f16x4 hi4 = *(const f16x4*)&Vt[vb + 16];
        f16x8 av;
        av[0] = lo4[0]; av[1] = lo4[1]; av[2] = lo4[2]; av[3] = lo4[3];
        av[4] = hi4[0]; av[5] = hi4[1]; av[6] = hi4[2]; av[7] = hi4[3];
        o = __builtin_amdgcn_mfma_f32_16x16x32_f16(av, __builtin_bit_cast(f16x8, bp), o, 0, 0, 0);
    }
    f4 res = o * inv;
    *(f4*)(wso + OFF_AO + ((size_t)(b * 256 + i0 + ln)) * 128 + h * 16 + q * 4) = res;
}

// ---------------- K5: output projection (MFMA) — 128 blocks x 4 waves ----------------
__global__ __launch_bounds__(256) void k_out(
    const float* __restrict__ ws, const _Float16* __restrict__ wp,
    const float* __restrict__ bo, float* __restrict__ out) {
    int tid = threadIdx.x;
    int lane = tid & 63, ln = lane & 15;
    int wid = blockIdx.x * 4 + (tid >> 6);       // 0..511
    int og = wid & 1, tg = wid >> 1;
    const _Float16* wpm = wp + UQKV + 3 * 32768;
    size_t tok = (size_t)(tg * 16 + ln);
    mfma_gemm64x16(ws + OFF_AO + tok * 128, wpm, og * 4, bo + og * 64,
                   out + tok * 128 + og * 64, lane);
}

extern "C" void kernel_launch(void* const* d_in, const int* in_sizes, int n_in,
                              void* d_out, int out_size, void* d_ws, size_t ws_size,
                              hipStream_t stream) {
    const float* x_pf   = (const float*)d_in[0];
    const float* x_feat = (const float*)d_in[1];
    const float* w0 = (const float*)d_in[2];
    const float* b0 = (const float*)d_in[3];
    const float* w1 = (const float*)d_in[4];
    const float* b1 = (const float*)d_in[5];
    const float* w2 = (const float*)d_in[6];
    const float* b2 = (const float*)d_in[7];
    const float* w3 = (const float*)d_in[8];
    const float* b3 = (const float*)d_in[9];
    const float* wq = (const float*)d_in[10];
    const float* wk = (const float*)d_in[11];
    const float* wv = (const float*)d_in[12];
    const float* wo = (const float*)d_in[13];
    const float* bq = (const float*)d_in[14];
    const float* bk = (const float*)d_in[15];
    const float* bv = (const float*)d_in[16];
    const float* bo = (const float*)d_in[17];
    float* ws  = (float*)d_ws;
    float* out = (float*)d_out;
    _Float16* wpack = (_Float16*)(ws + OFF_WPACK);

    hipLaunchKernelGGL(k_prep, dim3(64), dim3(256), 0, stream,
                       w0, w1, w2, w3, wq, wk, wv, wo, wpack);
    hipLaunchKernelGGL(k_particle, dim3(16), dim3(256), 0, stream, x_pf, ws);
    hipLaunchKernelGGL(k_pair_mlp, dim3(4096), dim3(256), 0, stream,
                       ws, wpack, b0, b1, b2, b3, ws + OFF_BIAS);
    hipLaunchKernelGGL(k_qkv, dim3(384), dim3(256), 0, stream,
                       x_feat, wpack, bq, bk, bv, ws);
    hipLaunchKernelGGL(k_attn, dim3(512), dim3(256), 0, stream, ws, ws);
    hipLaunchKernelGGL(k_out, dim3(128), dim3(256), 0, stream, ws, wpack, bo, out);
}

// Round 7
// 174.827 us; speedup vs baseline: 4.4435x; 1.1210x over previous
//
#include <hip/hip_runtime.h>
#include <hip/hip_bf16.h>
#include <math.h>

#define B_ 16
#define N_ 256
#define D_ 128
#define H_ 8
#define HD_ 16
#define EPS_ 1e-8f
#define PI_F 3.14159265358979323846f
#define TWO_PI_F 6.28318530717958647692f
#define INV_TWO_PI_F 0.15915494309189533577f
#define L2E_F 1.4426950408889634f

// ---------------- workspace layout (float units) ----------------
#define OFF_PT   0               // 4096
#define OFF_RAP  4096
#define OFF_PHI  8192
#define OFF_PX   12288
#define OFF_PY   16384
#define OFF_PZ   20480
#define OFF_E    24576
#define OFF_Q    28672           // 524288
#define OFF_K    (28672 + 524288)
#define OFF_V    (28672 + 2*524288)
#define OFF_BIAS (28672 + 3*524288)     // 8388608 floats (B,H,N,N)
#define OFF_AO   (OFF_BIAS + 8388608)   // 524288
#define OFF_WPACK (OFF_AO + 524288)     // packed f16 weight frags

// packed weight-frag offsets (f16 units, relative to wp)
#define UA0  0        // 2048 : layer0 combined hi/lo k-slot packing
#define UA1H 2048     // 4096
#define UA1L 6144     // 4096
#define UA2H 10240    // 4096
#define UA2L 14336    // 4096
#define UA3H 18432    // 1024
#define UA3L 19456    // 1024
#define UQKV 20480    // 4 matrices (wq,wk,wv,wo): each hi 16384 + lo 16384

typedef _Float16 f16x8 __attribute__((ext_vector_type(8)));
typedef _Float16 f16x4 __attribute__((ext_vector_type(4)));
typedef _Float16 f16x2 __attribute__((ext_vector_type(2)));
typedef __attribute__((ext_vector_type(4))) float f4;
typedef __attribute__((ext_vector_type(4))) unsigned int u4;

__device__ __forceinline__ unsigned pkh2(float a, float b) {
    f16x2 v = { (_Float16)a, (_Float16)b };          // RNE conversions
    return __builtin_bit_cast(unsigned, v);
}
__device__ __forceinline__ float f16res(float x) {   // exact residual of RNE f16
    return x - (float)(_Float16)x;
}

__device__ __forceinline__ float gelu_f(float x) {
    // tanh-approx gelu == x * sigmoid(y); y*log2e = 2.3022079x + 0.10294337x^3
    float y2 = x * fmaf(0.10294337f, x * x, 2.3022079f);
    float e = __builtin_amdgcn_exp2f(-y2);           // inf-safe both tails
    return x * __builtin_amdgcn_rcpf(1.0f + e);
}

// kappa permutation: k-slot (ks,q,j) <-> original index (2*(j>>2)+ks)*16 + q*4 + (j&3)

// ---------------- K_A: weight packing (blocks 0-63) + particle features (64-79) -------------
__global__ __launch_bounds__(256) void k_prep(
    const float* __restrict__ w0, const float* __restrict__ w1,
    const float* __restrict__ w2, const float* __restrict__ w3,
    const float* __restrict__ wq, const float* __restrict__ wk,
    const float* __restrict__ wv, const float* __restrict__ wo,
    const float* __restrict__ x_pf,
    _Float16* __restrict__ wp, float* __restrict__ ws) {
    if (blockIdx.x >= 64) {
        int idx = (blockIdx.x - 64) * 256 + threadIdx.x;   // 0..4095
        int b = idx >> 8, n = idx & 255;
        const float* base = x_pf + (size_t)b * 4 * N_;
        float px = base[0 * N_ + n];
        float py = base[1 * N_ + n];
        float pz = base[2 * N_ + n];
        float e  = base[3 * N_ + n];
        float pt  = sqrtf(fmaxf(px * px + py * py, EPS_));
        float rap = 0.5f * log1pf(2.0f * pz / fmaxf(e - pz, 1e-20f));
        float phi = atan2f(py, px);
        ws[OFF_PT  + idx] = pt;
        ws[OFF_RAP + idx] = rap;
        ws[OFF_PHI + idx] = phi;
        ws[OFF_PX  + idx] = px;
        ws[OFF_PY  + idx] = py;
        ws[OFF_PZ  + idx] = pz;
        ws[OFF_E   + idx] = e;
        return;
    }
    int id0 = blockIdx.x * 256 + threadIdx.x;
    const int gs = 64 * 256;
    // layer0: A slots (q=0): j0-3 = Whi rows, j4-7 = Wlo rows; (q=1): j0-3 = Whi, j4-7 = 0
    for (int e = id0; e < 2048; e += gs) {
        int fi = e >> 3, j = e & 7;
        int mt = fi >> 6, lane = fi & 63;
        int q = lane >> 4, ln = lane & 15;
        int m = mt * 16 + ln;
        _Float16 v = (_Float16)0.0f;
        if (q == 0) v = (j < 4) ? (_Float16)w0[j * 64 + m]
                                : (_Float16)f16res(w0[(j - 4) * 64 + m]);
        else if (q == 1) v = (j < 4) ? (_Float16)w0[j * 64 + m] : (_Float16)0.0f;
        wp[UA0 + e] = v;
    }
    // layers 1,2: frag fi = (mt*2+ks)*64 + lane; k-row kappa-permuted
    for (int e = id0; e < 4096; e += gs) {
        int fi = e >> 3, j = e & 7;
        int mt = fi >> 7, ks = (fi >> 6) & 1, lane = fi & 63;
        int q = lane >> 4;
        int m = mt * 16 + (lane & 15);
        int k = (2 * (j >> 2) + ks) * 16 + q * 4 + (j & 3);   // kappa
        float x1 = w1[k * 64 + m];
        wp[UA1H + e] = (_Float16)x1;
        wp[UA1L + e] = (_Float16)f16res(x1);
        float x2 = w2[k * 64 + m];
        wp[UA2H + e] = (_Float16)x2;
        wp[UA2L + e] = (_Float16)f16res(x2);
    }
    // layer3: single padded m-tile (rows 8..15 zero), kappa-permuted k
    for (int e = id0; e < 1024; e += gs) {
        int fi = e >> 3, j = e & 7;
        int ks = fi >> 6, lane = fi & 63;
        int q = lane >> 4;
        int m = lane & 15;
        int k = (2 * (j >> 2) + ks) * 16 + q * 4 + (j & 3);   // kappa
        float x = (m < 8) ? w3[k * 8 + m] : 0.0f;
        wp[UA3H + e] = (_Float16)x;
        wp[UA3L + e] = (_Float16)f16res(x);
    }
    // projection matrices: A[m=o][k=in], frag fi=(mt*4+ks)*64+lane (mt<8, ks<4)
    const float* mats[4] = { wq, wk, wv, wo };
#pragma unroll 1
    for (int mi = 0; mi < 4; ++mi) {
        const float* W = mats[mi];
        _Float16* dst = wp + UQKV + mi * 32768;
        for (int e = id0; e < 16384; e += gs) {
            int fi = e >> 3, j = e & 7;
            int mt = fi >> 8, ks = (fi >> 6) & 3, lane = fi & 63;
            int k = ks * 32 + ((lane >> 4) << 3) + j;
            int o = mt * 16 + (lane & 15);
            float x = W[k * 128 + o];
            dst[e] = (_Float16)x;
            dst[16384 + e] = (_Float16)f16res(x);
        }
    }
}

// epilogue: bias + gelu on C-layout accs, pack straight into next-layer B-frags (in-lane).
__device__ __forceinline__ void epi_frag(const f4 (&acc)[4][4], const float* __restrict__ bg,
                                         int q, u4 (&Bu)[4][2]) {
#pragma unroll
    for (int mt = 0; mt < 4; ++mt) {
        f4 bv = *(const f4*)&bg[mt * 16 + q * 4];
        int ks = mt & 1, hi = (mt >> 1) * 2;
#pragma unroll
        for (int nt = 0; nt < 4; ++nt) {
            float g0 = gelu_f(acc[mt][nt][0] + bv[0]);
            float g1 = gelu_f(acc[mt][nt][1] + bv[1]);
            float g2 = gelu_f(acc[mt][nt][2] + bv[2]);
            float g3 = gelu_f(acc[mt][nt][3] + bv[3]);
            Bu[nt][ks][hi]     = pkh2(g0, g1);
            Bu[nt][ks][hi + 1] = pkh2(g2, g3);
        }
    }
}

__device__ __forceinline__ void mid_layer(f4 (&acc)[4][4],
                                          const _Float16* __restrict__ wh,
                                          const _Float16* __restrict__ wl,
                                          int lane, const u4 (&Bu)[4][2]) {
    const f4 zero4 = { 0.f, 0.f, 0.f, 0.f };
#pragma unroll
    for (int mt = 0; mt < 4; ++mt) {
        f16x8 ah0 = *(const f16x8*)&wh[((mt * 2 + 0) * 64 + lane) * 8];
        f16x8 ah1 = *(const f16x8*)&wh[((mt * 2 + 1) * 64 + lane) * 8];
        f16x8 al0 = *(const f16x8*)&wl[((mt * 2 + 0) * 64 + lane) * 8];
        f16x8 al1 = *(const f16x8*)&wl[((mt * 2 + 1) * 64 + lane) * 8];
#pragma unroll
        for (int nt = 0; nt < 4; ++nt) {
            f16x8 b0 = __builtin_bit_cast(f16x8, Bu[nt][0]);
            f16x8 b1 = __builtin_bit_cast(f16x8, Bu[nt][1]);
            f4 c = zero4;
            c = __builtin_amdgcn_mfma_f32_16x16x32_f16(ah0, b0, c, 0, 0, 0);
            c = __builtin_amdgcn_mfma_f32_16x16x32_f16(al0, b0, c, 0, 0, 0);
            c = __builtin_amdgcn_mfma_f32_16x16x32_f16(ah1, b1, c, 0, 0, 0);
            c = __builtin_amdgcn_mfma_f32_16x16x32_f16(al1, b1, c, 0, 0, 0);
            acc[mt][nt] = c;
        }
    }
}

// ---------------- shared 64-out x 16-token split-f16 MFMA GEMM tile ----------------
__device__ __forceinline__ void mfma_gemm64x16(
    const float* __restrict__ xrow, const _Float16* __restrict__ wpm,
    int mtbase, const float* __restrict__ biasv, float* __restrict__ outp, int lane) {
    int q = lane >> 4;
    const f4 zero4 = { 0.f, 0.f, 0.f, 0.f };
    f16x8 Bh[4], Bl[4];
#pragma unroll
    for (int ks = 0; ks < 4; ++ks) {
        const float* p = xrow + ks * 32 + q * 8;
        float4 xa = ((const float4*)p)[0];
        float4 xb = ((const float4*)p)[1];
        u4 hu = { pkh2(xa.x, xa.y), pkh2(xa.z, xa.w), pkh2(xb.x, xb.y), pkh2(xb.z, xb.w) };
        u4 lu = { pkh2(f16res(xa.x), f16res(xa.y)), pkh2(f16res(xa.z), f16res(xa.w)),
                  pkh2(f16res(xb.x), f16res(xb.y)), pkh2(f16res(xb.z), f16res(xb.w)) };
        Bh[ks] = __builtin_bit_cast(f16x8, hu);
        Bl[ks] = __builtin_bit_cast(f16x8, lu);
    }
#pragma unroll
    for (int mtl = 0; mtl < 4; ++mtl) {
        int mt = mtbase + mtl;
        f4 c = zero4;
#pragma unroll
        for (int ks = 0; ks < 4; ++ks) {
            const _Float16* fa = wpm + ((size_t)((mt * 4 + ks) * 64 + lane)) * 8;
            f16x8 ah = *(const f16x8*)fa;
            f16x8 al = *(const f16x8*)(fa + 16384);
            c = __builtin_amdgcn_mfma_f32_16x16x32_f16(ah, Bh[ks], c, 0, 0, 0);
            c = __builtin_amdgcn_mfma_f32_16x16x32_f16(ah, Bl[ks], c, 0, 0, 0);
            c = __builtin_amdgcn_mfma_f32_16x16x32_f16(al, Bh[ks], c, 0, 0, 0);
        }
        f4 bv = *(const f4*)&biasv[mtl * 16 + q * 4];
        f4 r = c + bv;
        *(f4*)(outp + mtl * 16 + q * 4) = r;
    }
}

// ---------------- K_B: QKV (blocks 0-383) + symmetric pair MLP (blocks 384+) ----------
// pair part: 10240 waves; per b, 640 waves = rows i with j-slices jt >= it (upper triangle).
__global__ __launch_bounds__(256, 4) void k_pair_qkv(
    const float* __restrict__ ws, const _Float16* __restrict__ wp,
    const float* __restrict__ b0g, const float* __restrict__ b1g,
    const float* __restrict__ b2g, const float* __restrict__ b3g,
    float* __restrict__ bias_out,
    const float* __restrict__ xf,
    const float* __restrict__ bqv, const float* __restrict__ bkv, const float* __restrict__ bvv,
    float* __restrict__ qkv_out) {
    int tid = threadIdx.x;
    int lane = tid & 63;
    int ln = lane & 15, q = lane >> 4;

    if (blockIdx.x < 384) {
        // -------- QKV projection --------
        int wid = blockIdx.x * 4 + (tid >> 6);       // 0..1535
        int og = wid % 6, tg = wid / 6;
        int mi = og >> 1, ch = og & 1;
        const _Float16* wpm = wp + UQKV + mi * 32768;
        const float* bias = (mi == 0) ? bqv : ((mi == 1) ? bkv : bvv);
        float* outb = qkv_out + OFF_Q + (size_t)mi * 524288;
        size_t tok = (size_t)(tg * 16 + ln);
        mfma_gemm64x16(xf + tok * 128, wpm, ch * 4, bias + ch * 64,
                       outb + tok * 128 + ch * 64, lane);
        return;
    }

    // -------- pair MLP (upper-triangle wave-tiles) --------
    int w2 = (blockIdx.x - 384) * 4 + (tid >> 6);    // 0..10239
    int b = w2 / 640;
    int w = w2 - b * 640;
    int it, rr, nj;
    if (w < 256)      { it = 0; rr = w;       nj = 4; }
    else if (w < 448) { it = 1; rr = w - 256; nj = 3; }
    else if (w < 576) { it = 2; rr = w - 448; nj = 2; }
    else              { it = 3; rr = w - 576; nj = 1; }
    int i  = it * 64 + rr / nj;
    int jt = it + rr % nj;
    int j0 = jt * 64;
    int row = (b << 8) + i;

    unsigned FH01, FH23, FL01, FL23;
    {
        int ib = row;
        int jb = (b << 8) + j0 + lane;
        float pt_i = ws[OFF_PT + ib],  rap_i = ws[OFF_RAP + ib], phi_i = ws[OFF_PHI + ib];
        float px_i = ws[OFF_PX + ib],  py_i  = ws[OFF_PY  + ib];
        float pz_i = ws[OFF_PZ + ib],  e_i   = ws[OFF_E   + ib];
        float pt_j = ws[OFF_PT + jb],  rap_j = ws[OFF_RAP + jb], phi_j = ws[OFF_PHI + jb];
        float px_j = ws[OFF_PX + jb],  py_j  = ws[OFF_PY  + jb];
        float pz_j = ws[OFF_PZ + jb],  e_j   = ws[OFF_E   + jb];

        float drap = rap_i - rap_j;
        float xw = phi_i - phi_j + PI_F;
        float mw = xw - TWO_PI_F * floorf(xw * INV_TWO_PI_F);
        float dphi = mw - PI_F;
        float delta = sqrtf(drap * drap + dphi * dphi);
        float f2 = __logf(fmaxf(delta, EPS_));
        float ptmin = fminf(pt_i, pt_j);
        float f0 = __logf(fmaxf(ptmin * delta, EPS_));
        float f1 = __logf(fmaxf(ptmin / fmaxf(pt_i + pt_j, EPS_), EPS_));
        float es = e_i + e_j, pxs = px_i + px_j, pys = py_i + py_j, pzs = pz_i + pz_j;
        float f3 = __logf(fmaxf(es * es - pxs * pxs - pys * pys - pzs * pzs, EPS_));

        FH01 = pkh2(f0, f1);
        FH23 = pkh2(f2, f3);
        FL01 = pkh2(f16res(f0), f16res(f1));
        FL23 = pkh2(f16res(f2), f16res(f3));
    }

    f4 acc[4][4];
    const f4 zero4 = { 0.f, 0.f, 0.f, 0.f };

    // layer 0: 4 -> 64
    {
        f16x8 a0[4];
#pragma unroll
        for (int mt = 0; mt < 4; ++mt)
            a0[mt] = *(const f16x8*)&wp[UA0 + (mt * 64 + lane) * 8];
#pragma unroll
        for (int nt = 0; nt < 4; ++nt) {
            int src = nt * 16 + ln;
            unsigned h01 = (unsigned)__shfl((int)FH01, src);
            unsigned h23 = (unsigned)__shfl((int)FH23, src);
            unsigned l01 = (unsigned)__shfl((int)FL01, src);
            unsigned l23 = (unsigned)__shfl((int)FL23, src);
            u4 bu;
            bu[0] = (q == 0) ? h01 : ((q == 1) ? l01 : 0u);
            bu[1] = (q == 0) ? h23 : ((q == 1) ? l23 : 0u);
            bu[2] = (q == 0) ? h01 : 0u;
            bu[3] = (q == 0) ? h23 : 0u;
            f16x8 bf = __builtin_bit_cast(f16x8, bu);
#pragma unroll
            for (int mt = 0; mt < 4; ++mt)
                acc[mt][nt] = __builtin_amdgcn_mfma_f32_16x16x32_f16(a0[mt], bf, zero4, 0, 0, 0);
        }
    }

    u4 Bu[4][2];
    epi_frag(acc, b0g, q, Bu);
    mid_layer(acc, wp + UA1H, wp + UA1L, lane, Bu);
    epi_frag(acc, b1g, q, Bu);
    mid_layer(acc, wp + UA2H, wp + UA2L, lane, Bu);
    epi_frag(acc, b2g, q, Bu);

    // layer 3: 64 -> 8, write row segment + (off-diagonal) mirrored column segment
    {
        f16x8 a3h0 = *(const f16x8*)&wp[UA3H + (0 * 64 + lane) * 8];
        f16x8 a3h1 = *(const f16x8*)&wp[UA3H + (1 * 64 + lane) * 8];
        f16x8 a3l0 = *(const f16x8*)&wp[UA3L + (0 * 64 + lane) * 8];
        f16x8 a3l1 = *(const f16x8*)&wp[UA3L + (1 * 64 + lane) * 8];
        f4 acc3[4];
#pragma unroll
        for (int nt = 0; nt < 4; ++nt) {
            f16x8 b0 = __builtin_bit_cast(f16x8, Bu[nt][0]);
            f16x8 b1 = __builtin_bit_cast(f16x8, Bu[nt][1]);
            f4 c = zero4;
            c = __builtin_amdgcn_mfma_f32_16x16x32_f16(a3h0, b0, c, 0, 0, 0);
            c = __builtin_amdgcn_mfma_f32_16x16x32_f16(a3l0, b0, c, 0, 0, 0);
            c = __builtin_amdgcn_mfma_f32_16x16x32_f16(a3h1, b1, c, 0, 0, 0);
            c = __builtin_amdgcn_mfma_f32_16x16x32_f16(a3l1, b1, c, 0, 0, 0);
            acc3[nt] = c;
        }
        if (q < 2) {
            f4 b3v = *(const f4*)&b3g[q * 4];
            bool mirror = (jt != it);
#pragma unroll
            for (int nt = 0; nt < 4; ++nt) {
                int jc = j0 + nt * 16 + ln;
#pragma unroll
                for (int r = 0; r < 4; ++r) {
                    int out = q * 4 + r;
                    float val = acc3[nt][r] + b3v[r];
                    size_t basebh = ((size_t)(b * H_ + out)) * N_;
                    bias_out[(basebh + i) * N_ + jc] = val;
                    if (mirror) bias_out[(basebh + jc) * N_ + i] = val;
                }
            }
        }
    }
}

// ---------------- K_C: attention (MFMA flash-row) — 512 blocks x 4 waves ----------------
#define SVT 264   // f16 stride of transposed V in LDS (264 = 4 mod 32 banks -> 2-way only)
__global__ __launch_bounds__(256) void k_attn(const float* __restrict__ ws,
                                              float* __restrict__ wso) {
    __shared__ __align__(16) _Float16 Vt[16 * SVT];
    int tid = threadIdx.x;
    int blk = blockIdx.x;                 // (b*8+h)*4 + ib
    int ib = blk & 3;
    int bh = blk >> 2;
    int b = bh >> 3, h = bh & 7;

    // stage V transposed: Vt[d][j] f16
    {
        const float* vr = ws + OFF_V + ((size_t)(b * 256 + tid)) * 128 + h * 16;
        float4 v0 = ((const float4*)vr)[0];
        float4 v1 = ((const float4*)vr)[1];
        float4 v2 = ((const float4*)vr)[2];
        float4 v3 = ((const float4*)vr)[3];
        Vt[ 0 * SVT + tid] = (_Float16)v0.x;  Vt[ 1 * SVT + tid] = (_Float16)v0.y;
        Vt[ 2 * SVT + tid] = (_Float16)v0.z;  Vt[ 3 * SVT + tid] = (_Float16)v0.w;
        Vt[ 4 * SVT + tid] = (_Float16)v1.x;  Vt[ 5 * SVT + tid] = (_Float16)v1.y;
        Vt[ 6 * SVT + tid] = (_Float16)v1.z;  Vt[ 7 * SVT + tid] = (_Float16)v1.w;
        Vt[ 8 * SVT + tid] = (_Float16)v2.x;  Vt[ 9 * SVT + tid] = (_Float16)v2.y;
        Vt[10 * SVT + tid] = (_Float16)v2.z;  Vt[11 * SVT + tid] = (_Float16)v2.w;
        Vt[12 * SVT + tid] = (_Float16)v3.x;  Vt[13 * SVT + tid] = (_Float16)v3.y;
        Vt[14 * SVT + tid] = (_Float16)v3.z;  Vt[15 * SVT + tid] = (_Float16)v3.w;
    }
    __syncthreads();

    int lane = tid & 63, w = tid >> 6;
    int ln = lane & 15, q = lane >> 4;
    int i0 = ib * 64 + w * 16;
    const f4 zero4 = { 0.f, 0.f, 0.f, 0.f };

    // B_Q: [Qh | Qh] across K=32 slots (d-half selected by q&1)
    f16x8 Bq;
    {
        const float* qr = ws + OFF_Q + ((size_t)(b * 256 + i0 + ln)) * 128 + h * 16 + (q & 1) * 8;
        float4 qa = ((const float4*)qr)[0];
        float4 qb = ((const float4*)qr)[1];
        u4 hu = { pkh2(qa.x, qa.y), pkh2(qa.z, qa.w), pkh2(qb.x, qb.y), pkh2(qb.z, qb.w) };
        Bq = __builtin_bit_cast(f16x8, hu);
    }

    // S^T = K · Q^T : A = [K_hi (q<2) | K_lo (q>=2)], 16 m-tiles over j
    f4 accs[16];
    const float* Kbase = ws + OFF_K + ((size_t)(b * 256)) * 128 + h * 16;
    const float* bb = ws + OFF_BIAS + ((size_t)(bh * 256 + i0 + ln)) * 256 + q * 4;
#pragma unroll
    for (int mt = 0; mt < 16; ++mt) {
        const float* kr = Kbase + (size_t)(mt * 16 + ln) * 128 + (q & 1) * 8;
        float4 ka = ((const float4*)kr)[0];
        float4 kb = ((const float4*)kr)[1];
        u4 hu = { pkh2(ka.x, ka.y), pkh2(ka.z, ka.w), pkh2(kb.x, kb.y), pkh2(kb.z, kb.w) };
        u4 lu = { pkh2(f16res(ka.x), f16res(ka.y)), pkh2(f16res(ka.z), f16res(ka.w)),
                  pkh2(f16res(kb.x), f16res(kb.y)), pkh2(f16res(kb.z), f16res(kb.w)) };
        u4 au;
        bool qlo = (q < 2);
        au[0] = qlo ? hu[0] : lu[0];
        au[1] = qlo ? hu[1] : lu[1];
        au[2] = qlo ? hu[2] : lu[2];
        au[3] = qlo ? hu[3] : lu[3];
        f16x8 Ak = __builtin_bit_cast(f16x8, au);
        f4 s = __builtin_amdgcn_mfma_f32_16x16x32_f16(Ak, Bq, zero4, 0, 0, 0);
        f4 bias4 = *(const f4*)&bb[mt * 16];
#pragma unroll
        for (int r = 0; r < 4; ++r) s[r] = fmaf(s[r], 0.25f, bias4[r]);
        accs[mt] = s;
    }

    // softmax over j (64 in-lane values + cross-q reduce; i = ln fixed per lane)
    float mx = accs[0][0];
#pragma unroll
    for (int mt = 0; mt < 16; ++mt)
#pragma unroll
        for (int r = 0; r < 4; ++r) mx = fmaxf(mx, accs[mt][r]);
    mx = fmaxf(mx, __shfl_xor(mx, 16));
    mx = fmaxf(mx, __shfl_xor(mx, 32));
    float nms = -mx * L2E_F;
    float l = 0.0f;
#pragma unroll
    for (int mt = 0; mt < 16; ++mt) {
#pragma unroll
        for (int r = 0; r < 4; ++r) {
            float p = __builtin_amdgcn_exp2f(fmaf(accs[mt][r], L2E_F, nms));
            accs[mt][r] = p;
            l += p;
        }
    }
    l += __shfl_xor(l, 16);
    l += __shfl_xor(l, 32);
    float inv = __builtin_amdgcn_rcpf(l);

    // O^T = V^T_perm · P^T  (kappa: in-lane P pack, permuted V read)
    f4 o = zero4;
#pragma unroll
    for (int ks = 0; ks < 8; ++ks) {
        u4 bp = { pkh2(accs[2 * ks][0], accs[2 * ks][1]),
                  pkh2(accs[2 * ks][2], accs[2 * ks][3]),
                  pkh2(accs[2 * ks + 1][0], accs[2 * ks + 1][1]),
                  pkh2(accs[2 * ks + 1][2], accs[2 * ks + 1][3]) };
        int vb = ln * SVT + 32 * ks + 4 * q;
        f16x4 lo4 = *(const f16x4*)&Vt[vb];
        f16x4 hi4 = *(const f16x4*)&Vt[vb + 16];
        f16x8 av;
        av[0] = lo4[0]; av[1] = lo4[1]; av[2] = lo4[2]; av[3] = lo4[3];
        av[4] = hi4[0]; av[5] = hi4[1]; av[6] = hi4[2]; av[7] = hi4[3];
        o = __builtin_amdgcn_mfma_f32_16x16x32_f16(av, __builtin_bit_cast(f16x8, bp), o, 0, 0, 0);
    }
    f4 res = o * inv;
    *(f4*)(wso + OFF_AO + ((size_t)(b * 256 + i0 + ln)) * 128 + h * 16 + q * 4) = res;
}

// ---------------- K_D: output projection (MFMA) — 128 blocks x 4 waves ----------------
__global__ __launch_bounds__(256) void k_out(
    const float* __restrict__ ws, const _Float16* __restrict__ wp,
    const float* __restrict__ bo, float* __restrict__ out) {
    int tid = threadIdx.x;
    int lane = tid & 63, ln = lane & 15;
    int wid = blockIdx.x * 4 + (tid >> 6);       // 0..511
    int og = wid & 1, tg = wid >> 1;
    const _Float16* wpm = wp + UQKV + 3 * 32768;
    size_t tok = (size_t)(tg * 16 + ln);
    mfma_gemm64x16(ws + OFF_AO + tok * 128, wpm, og * 4, bo + og * 64,
                   out + tok * 128 + og * 64, lane);
}

extern "C" void kernel_launch(void* const* d_in, const int* in_sizes, int n_in,
                              void* d_out, int out_size, void* d_ws, size_t ws_size,
                              hipStream_t stream) {
    const float* x_pf   = (const float*)d_in[0];
    const float* x_feat = (const float*)d_in[1];
    const float* w0 = (const float*)d_in[2];
    const float* b0 = (const float*)d_in[3];
    const float* w1 = (const float*)d_in[4];
    const float* b1 = (const float*)d_in[5];
    const float* w2 = (const float*)d_in[6];
    const float* b2 = (const float*)d_in[7];
    const float* w3 = (const float*)d_in[8];
    const float* b3 = (const float*)d_in[9];
    const float* wq = (const float*)d_in[10];
    const float* wk = (const float*)d_in[11];
    const float* wv = (const float*)d_in[12];
    const float* wo = (const float*)d_in[13];
    const float* bq = (const float*)d_in[14];
    const float* bk = (const float*)d_in[15];
    const float* bv = (const float*)d_in[16];
    const float* bo = (const float*)d_in[17];
    float* ws  = (float*)d_ws;
    float* out = (float*)d_out;
    _Float16* wpack = (_Float16*)(ws + OFF_WPACK);

    hipLaunchKernelGGL(k_prep, dim3(80), dim3(256), 0, stream,
                       w0, w1, w2, w3, wq, wk, wv, wo, x_pf, wpack, ws);
    hipLaunchKernelGGL(k_pair_qkv, dim3(384 + 2560), dim3(256), 0, stream,
                       ws, wpack, b0, b1, b2, b3, ws + OFF_BIAS,
                       x_feat, bq, bk, bv, ws);
    hipLaunchKernelGGL(k_attn, dim3(512), dim3(256), 0, stream, ws, ws);
    hipLaunchKernelGGL(k_out, dim3(128), dim3(256), 0, stream, ws, wpack, bo, out);
}

// Round 8
// 161.400 us; speedup vs baseline: 4.8131x; 1.0832x over previous
//
#include <hip/hip_runtime.h>
#include <hip/hip_bf16.h>
#include <math.h>

#define B_ 16
#define N_ 256
#define D_ 128
#define H_ 8
#define HD_ 16
#define EPS_ 1e-8f
#define PI_F 3.14159265358979323846f
#define TWO_PI_F 6.28318530717958647692f
#define INV_TWO_PI_F 0.15915494309189533577f
#define L2E_F 1.4426950408889634f

// ---------------- workspace layout (float units) ----------------
#define OFF_PT   0               // 4096
#define OFF_RAP  4096
#define OFF_PHI  8192
#define OFF_PX   12288
#define OFF_PY   16384
#define OFF_PZ   20480
#define OFF_E    24576
#define OFF_Q    28672           // f16 region: QH/KH/KL/VH, each 524288 f16 (4 MB total)
#define OFF_BIAS (28672 + 3*524288)     // 8388608 floats (B,H,N,N), upper-tri tiles only
#define OFF_AO   (OFF_BIAS + 8388608)   // 524288
#define OFF_WPACK (OFF_AO + 524288)     // packed f16 weight frags

// packed weight-frag offsets (f16 units, relative to wp)
#define UA0  0        // 2048 : layer0 combined hi/lo k-slot packing
#define UA1H 2048     // 4096
#define UA1L 6144     // 4096
#define UA2H 10240    // 4096
#define UA2L 14336    // 4096
#define UA3H 18432    // 1024
#define UA3L 19456    // 1024
#define UQKV 20480    // 4 matrices (wq,wk,wv,wo): each hi 16384 + lo 16384

typedef _Float16 f16x8 __attribute__((ext_vector_type(8)));
typedef _Float16 f16x4 __attribute__((ext_vector_type(4)));
typedef _Float16 f16x2 __attribute__((ext_vector_type(2)));
typedef __attribute__((ext_vector_type(4))) float f4;
typedef __attribute__((ext_vector_type(4))) unsigned int u4;

__device__ __forceinline__ unsigned pkh2(float a, float b) {
    f16x2 v = { (_Float16)a, (_Float16)b };          // RNE conversions
    return __builtin_bit_cast(unsigned, v);
}
__device__ __forceinline__ float f16res(float x) {   // exact residual of RNE f16
    return x - (float)(_Float16)x;
}

__device__ __forceinline__ float gelu_f(float x) {
    // tanh-approx gelu == x * sigmoid(y); y*log2e = 2.3022079x + 0.10294337x^3
    float y2 = x * fmaf(0.10294337f, x * x, 2.3022079f);
    float e = __builtin_amdgcn_exp2f(-y2);           // inf-safe both tails
    return x * __builtin_amdgcn_rcpf(1.0f + e);
}

// kappa permutation: k-slot (ks,q,j) <-> original index (2*(j>>2)+ks)*16 + q*4 + (j&3)

// ---------------- K_A: weight packing (blocks 0-63) + particle features (64-79) -------------
__global__ __launch_bounds__(256) void k_prep(
    const float* __restrict__ w0, const float* __restrict__ w1,
    const float* __restrict__ w2, const float* __restrict__ w3,
    const float* __restrict__ wq, const float* __restrict__ wk,
    const float* __restrict__ wv, const float* __restrict__ wo,
    const float* __restrict__ x_pf,
    _Float16* __restrict__ wp, float* __restrict__ ws) {
    if (blockIdx.x >= 64) {
        int idx = (blockIdx.x - 64) * 256 + threadIdx.x;   // 0..4095
        int b = idx >> 8, n = idx & 255;
        const float* base = x_pf + (size_t)b * 4 * N_;
        float px = base[0 * N_ + n];
        float py = base[1 * N_ + n];
        float pz = base[2 * N_ + n];
        float e  = base[3 * N_ + n];
        float pt  = sqrtf(fmaxf(px * px + py * py, EPS_));
        float rap = 0.5f * log1pf(2.0f * pz / fmaxf(e - pz, 1e-20f));
        float phi = atan2f(py, px);
        ws[OFF_PT  + idx] = pt;
        ws[OFF_RAP + idx] = rap;
        ws[OFF_PHI + idx] = phi;
        ws[OFF_PX  + idx] = px;
        ws[OFF_PY  + idx] = py;
        ws[OFF_PZ  + idx] = pz;
        ws[OFF_E   + idx] = e;
        return;
    }
    int id0 = blockIdx.x * 256 + threadIdx.x;
    const int gs = 64 * 256;
    for (int e = id0; e < 2048; e += gs) {
        int fi = e >> 3, j = e & 7;
        int mt = fi >> 6, lane = fi & 63;
        int q = lane >> 4, ln = lane & 15;
        int m = mt * 16 + ln;
        _Float16 v = (_Float16)0.0f;
        if (q == 0) v = (j < 4) ? (_Float16)w0[j * 64 + m]
                                : (_Float16)f16res(w0[(j - 4) * 64 + m]);
        else if (q == 1) v = (j < 4) ? (_Float16)w0[j * 64 + m] : (_Float16)0.0f;
        wp[UA0 + e] = v;
    }
    for (int e = id0; e < 4096; e += gs) {
        int fi = e >> 3, j = e & 7;
        int mt = fi >> 7, ks = (fi >> 6) & 1, lane = fi & 63;
        int q = lane >> 4;
        int m = mt * 16 + (lane & 15);
        int k = (2 * (j >> 2) + ks) * 16 + q * 4 + (j & 3);   // kappa
        float x1 = w1[k * 64 + m];
        wp[UA1H + e] = (_Float16)x1;
        wp[UA1L + e] = (_Float16)f16res(x1);
        float x2 = w2[k * 64 + m];
        wp[UA2H + e] = (_Float16)x2;
        wp[UA2L + e] = (_Float16)f16res(x2);
    }
    for (int e = id0; e < 1024; e += gs) {
        int fi = e >> 3, j = e & 7;
        int ks = fi >> 6, lane = fi & 63;
        int q = lane >> 4;
        int m = lane & 15;
        int k = (2 * (j >> 2) + ks) * 16 + q * 4 + (j & 3);   // kappa
        float x = (m < 8) ? w3[k * 8 + m] : 0.0f;
        wp[UA3H + e] = (_Float16)x;
        wp[UA3L + e] = (_Float16)f16res(x);
    }
    const float* mats[4] = { wq, wk, wv, wo };
#pragma unroll 1
    for (int mi = 0; mi < 4; ++mi) {
        const float* W = mats[mi];
        _Float16* dst = wp + UQKV + mi * 32768;
        for (int e = id0; e < 16384; e += gs) {
            int fi = e >> 3, j = e & 7;
            int mt = fi >> 8, ks = (fi >> 6) & 3, lane = fi & 63;
            int k = ks * 32 + ((lane >> 4) << 3) + j;
            int o = mt * 16 + (lane & 15);
            float x = W[k * 128 + o];
            dst[e] = (_Float16)x;
            dst[16384 + e] = (_Float16)f16res(x);
        }
    }
}

// epilogue: bias + gelu on C-layout accs, pack straight into next-layer B-frags (in-lane).
__device__ __forceinline__ void epi_frag(const f4 (&acc)[4][4], const float* __restrict__ bg,
                                         int q, u4 (&Bu)[4][2]) {
#pragma unroll
    for (int mt = 0; mt < 4; ++mt) {
        f4 bv = *(const f4*)&bg[mt * 16 + q * 4];
        int ks = mt & 1, hi = (mt >> 1) * 2;
#pragma unroll
        for (int nt = 0; nt < 4; ++nt) {
            float g0 = gelu_f(acc[mt][nt][0] + bv[0]);
            float g1 = gelu_f(acc[mt][nt][1] + bv[1]);
            float g2 = gelu_f(acc[mt][nt][2] + bv[2]);
            float g3 = gelu_f(acc[mt][nt][3] + bv[3]);
            Bu[nt][ks][hi]     = pkh2(g0, g1);
            Bu[nt][ks][hi + 1] = pkh2(g2, g3);
        }
    }
}

__device__ __forceinline__ void mid_layer(f4 (&acc)[4][4],
                                          const _Float16* __restrict__ wh,
                                          const _Float16* __restrict__ wl,
                                          int lane, const u4 (&Bu)[4][2]) {
    const f4 zero4 = { 0.f, 0.f, 0.f, 0.f };
#pragma unroll
    for (int mt = 0; mt < 4; ++mt) {
        f16x8 ah0 = *(const f16x8*)&wh[((mt * 2 + 0) * 64 + lane) * 8];
        f16x8 ah1 = *(const f16x8*)&wh[((mt * 2 + 1) * 64 + lane) * 8];
        f16x8 al0 = *(const f16x8*)&wl[((mt * 2 + 0) * 64 + lane) * 8];
        f16x8 al1 = *(const f16x8*)&wl[((mt * 2 + 1) * 64 + lane) * 8];
#pragma unroll
        for (int nt = 0; nt < 4; ++nt) {
            f16x8 b0 = __builtin_bit_cast(f16x8, Bu[nt][0]);
            f16x8 b1 = __builtin_bit_cast(f16x8, Bu[nt][1]);
            f4 c = zero4;
            c = __builtin_amdgcn_mfma_f32_16x16x32_f16(ah0, b0, c, 0, 0, 0);
            c = __builtin_amdgcn_mfma_f32_16x16x32_f16(al0, b0, c, 0, 0, 0);
            c = __builtin_amdgcn_mfma_f32_16x16x32_f16(ah1, b1, c, 0, 0, 0);
            c = __builtin_amdgcn_mfma_f32_16x16x32_f16(al1, b1, c, 0, 0, 0);
            acc[mt][nt] = c;
        }
    }
}

// ---------------- split-f16 64-out x 16-token MFMA core ----------------
__device__ __forceinline__ void mfma_core64x16(
    const float* __restrict__ xrow, const _Float16* __restrict__ wpm,
    int mtbase, const float* __restrict__ biasv, int lane, f4 (&cc)[4]) {
    int q = lane >> 4;
    const f4 zero4 = { 0.f, 0.f, 0.f, 0.f };
    f16x8 Bh[4], Bl[4];
#pragma unroll
    for (int ks = 0; ks < 4; ++ks) {
        const float* p = xrow + ks * 32 + q * 8;
        float4 xa = ((const float4*)p)[0];
        float4 xb = ((const float4*)p)[1];
        u4 hu = { pkh2(xa.x, xa.y), pkh2(xa.z, xa.w), pkh2(xb.x, xb.y), pkh2(xb.z, xb.w) };
        u4 lu = { pkh2(f16res(xa.x), f16res(xa.y)), pkh2(f16res(xa.z), f16res(xa.w)),
                  pkh2(f16res(xb.x), f16res(xb.y)), pkh2(f16res(xb.z), f16res(xb.w)) };
        Bh[ks] = __builtin_bit_cast(f16x8, hu);
        Bl[ks] = __builtin_bit_cast(f16x8, lu);
    }
#pragma unroll
    for (int mtl = 0; mtl < 4; ++mtl) {
        int mt = mtbase + mtl;
        f4 c = zero4;
#pragma unroll
        for (int ks = 0; ks < 4; ++ks) {
            const _Float16* fa = wpm + ((size_t)((mt * 4 + ks) * 64 + lane)) * 8;
            f16x8 ah = *(const f16x8*)fa;
            f16x8 al = *(const f16x8*)(fa + 16384);
            c = __builtin_amdgcn_mfma_f32_16x16x32_f16(ah, Bh[ks], c, 0, 0, 0);
            c = __builtin_amdgcn_mfma_f32_16x16x32_f16(ah, Bl[ks], c, 0, 0, 0);
            c = __builtin_amdgcn_mfma_f32_16x16x32_f16(al, Bh[ks], c, 0, 0, 0);
        }
        f4 bv = *(const f4*)&biasv[mtl * 16 + q * 4];
        cc[mtl] = c + bv;
    }
}

// ---------------- K_B: QKV (blocks 0-383) + symmetric pair MLP (blocks 384+) ----------
__global__ __launch_bounds__(256, 4) void k_pair_qkv(
    const float* __restrict__ ws, const _Float16* __restrict__ wp,
    const float* __restrict__ b0g, const float* __restrict__ b1g,
    const float* __restrict__ b2g, const float* __restrict__ b3g,
    float* __restrict__ bias_out,
    const float* __restrict__ xf,
    const float* __restrict__ bqv, const float* __restrict__ bkv, const float* __restrict__ bvv,
    _Float16* __restrict__ qh, _Float16* __restrict__ kh,
    _Float16* __restrict__ kl, _Float16* __restrict__ vh) {
    int tid = threadIdx.x;
    int lane = tid & 63;
    int ln = lane & 15, q = lane >> 4;

    if (blockIdx.x < 384) {
        // -------- QKV projection -> packed f16 outputs --------
        int wid = blockIdx.x * 4 + (tid >> 6);       // 0..1535
        int og = wid % 6, tg = wid / 6;
        int mi = og >> 1, ch = og & 1;
        const _Float16* wpm = wp + UQKV + mi * 32768;
        const float* bias = (mi == 0) ? bqv : ((mi == 1) ? bkv : bvv);
        size_t tok = (size_t)(tg * 16 + ln);
        f4 cc[4];
        mfma_core64x16(xf + tok * 128, wpm, ch * 4, bias + ch * 64, lane, cc);
        _Float16* hout = (mi == 0) ? qh : ((mi == 1) ? kh : vh);
#pragma unroll
        for (int mtl = 0; mtl < 4; ++mtl) {
            size_t off = tok * 128 + ch * 64 + mtl * 16 + q * 4;
            f16x4 hv;
#pragma unroll
            for (int r = 0; r < 4; ++r) hv[r] = (_Float16)cc[mtl][r];
            *(f16x4*)&hout[off] = hv;
            if (mi == 1) {
                f16x4 lv;
#pragma unroll
                for (int r = 0; r < 4; ++r) lv[r] = (_Float16)(cc[mtl][r] - (float)hv[r]);
                *(f16x4*)&kl[off] = lv;
            }
        }
        return;
    }

    // -------- pair MLP (upper-triangle wave-tiles; no mirror writes) --------
    int w2 = (blockIdx.x - 384) * 4 + (tid >> 6);    // 0..10239
    int b = w2 / 640;
    int w = w2 - b * 640;
    int it, rr, nj;
    if (w < 256)      { it = 0; rr = w;       nj = 4; }
    else if (w < 448) { it = 1; rr = w - 256; nj = 3; }
    else if (w < 576) { it = 2; rr = w - 448; nj = 2; }
    else              { it = 3; rr = w - 576; nj = 1; }
    int i  = it * 64 + rr / nj;
    int jt = it + rr % nj;
    int j0 = jt * 64;
    int row = (b << 8) + i;

    unsigned FH01, FH23, FL01, FL23;
    {
        int ib = row;
        int jb = (b << 8) + j0 + lane;
        float pt_i = ws[OFF_PT + ib],  rap_i = ws[OFF_RAP + ib], phi_i = ws[OFF_PHI + ib];
        float px_i = ws[OFF_PX + ib],  py_i  = ws[OFF_PY  + ib];
        float pz_i = ws[OFF_PZ + ib],  e_i   = ws[OFF_E   + ib];
        float pt_j = ws[OFF_PT + jb],  rap_j = ws[OFF_RAP + jb], phi_j = ws[OFF_PHI + jb];
        float px_j = ws[OFF_PX + jb],  py_j  = ws[OFF_PY  + jb];
        float pz_j = ws[OFF_PZ + jb],  e_j   = ws[OFF_E   + jb];

        float drap = rap_i - rap_j;
        float xw = phi_i - phi_j + PI_F;
        float mw = xw - TWO_PI_F * floorf(xw * INV_TWO_PI_F);
        float dphi = mw - PI_F;
        float delta = sqrtf(drap * drap + dphi * dphi);
        float f2 = __logf(fmaxf(delta, EPS_));
        float ptmin = fminf(pt_i, pt_j);
        float f0 = __logf(fmaxf(ptmin * delta, EPS_));
        float f1 = __logf(fmaxf(ptmin / fmaxf(pt_i + pt_j, EPS_), EPS_));
        float es = e_i + e_j, pxs = px_i + px_j, pys = py_i + py_j, pzs = pz_i + pz_j;
        float f3 = __logf(fmaxf(es * es - pxs * pxs - pys * pys - pzs * pzs, EPS_));

        FH01 = pkh2(f0, f1);
        FH23 = pkh2(f2, f3);
        FL01 = pkh2(f16res(f0), f16res(f1));
        FL23 = pkh2(f16res(f2), f16res(f3));
    }

    f4 acc[4][4];
    const f4 zero4 = { 0.f, 0.f, 0.f, 0.f };

    // layer 0: 4 -> 64
    {
        f16x8 a0[4];
#pragma unroll
        for (int mt = 0; mt < 4; ++mt)
            a0[mt] = *(const f16x8*)&wp[UA0 + (mt * 64 + lane) * 8];
#pragma unroll
        for (int nt = 0; nt < 4; ++nt) {
            int src = nt * 16 + ln;
            unsigned h01 = (unsigned)__shfl((int)FH01, src);
            unsigned h23 = (unsigned)__shfl((int)FH23, src);
            unsigned l01 = (unsigned)__shfl((int)FL01, src);
            unsigned l23 = (unsigned)__shfl((int)FL23, src);
            u4 bu;
            bu[0] = (q == 0) ? h01 : ((q == 1) ? l01 : 0u);
            bu[1] = (q == 0) ? h23 : ((q == 1) ? l23 : 0u);
            bu[2] = (q == 0) ? h01 : 0u;
            bu[3] = (q == 0) ? h23 : 0u;
            f16x8 bf = __builtin_bit_cast(f16x8, bu);
#pragma unroll
            for (int mt = 0; mt < 4; ++mt)
                acc[mt][nt] = __builtin_amdgcn_mfma_f32_16x16x32_f16(a0[mt], bf, zero4, 0, 0, 0);
        }
    }

    u4 Bu[4][2];
    epi_frag(acc, b0g, q, Bu);
    mid_layer(acc, wp + UA1H, wp + UA1L, lane, Bu);
    epi_frag(acc, b1g, q, Bu);
    mid_layer(acc, wp + UA2H, wp + UA2L, lane, Bu);
    epi_frag(acc, b2g, q, Bu);

    // layer 3: 64 -> 8, coalesced row-segment write only
    {
        f16x8 a3h0 = *(const f16x8*)&wp[UA3H + (0 * 64 + lane) * 8];
        f16x8 a3h1 = *(const f16x8*)&wp[UA3H + (1 * 64 + lane) * 8];
        f16x8 a3l0 = *(const f16x8*)&wp[UA3L + (0 * 64 + lane) * 8];
        f16x8 a3l1 = *(const f16x8*)&wp[UA3L + (1 * 64 + lane) * 8];
        f4 acc3[4];
#pragma unroll
        for (int nt = 0; nt < 4; ++nt) {
            f16x8 b0 = __builtin_bit_cast(f16x8, Bu[nt][0]);
            f16x8 b1 = __builtin_bit_cast(f16x8, Bu[nt][1]);
            f4 c = zero4;
            c = __builtin_amdgcn_mfma_f32_16x16x32_f16(a3h0, b0, c, 0, 0, 0);
            c = __builtin_amdgcn_mfma_f32_16x16x32_f16(a3l0, b0, c, 0, 0, 0);
            c = __builtin_amdgcn_mfma_f32_16x16x32_f16(a3h1, b1, c, 0, 0, 0);
            c = __builtin_amdgcn_mfma_f32_16x16x32_f16(a3l1, b1, c, 0, 0, 0);
            acc3[nt] = c;
        }
        if (q < 2) {
            f4 b3v = *(const f4*)&b3g[q * 4];
#pragma unroll
            for (int nt = 0; nt < 4; ++nt) {
                int jc = j0 + nt * 16 + ln;
#pragma unroll
                for (int r = 0; r < 4; ++r) {
                    int out = q * 4 + r;
                    bias_out[(((size_t)(b * H_ + out)) * N_ + i) * N_ + jc] = acc3[nt][r] + b3v[r];
                }
            }
        }
    }
}

// ---------------- K_C: attention (MFMA flash-row, f16 pre-packed QKV) ----------------
#define SVT 264   // f16 stride of transposed V in LDS (264 = 4 mod 32 banks -> 2-way only)
__global__ __launch_bounds__(256) void k_attn(
    const float* __restrict__ ws,
    const _Float16* __restrict__ qh, const _Float16* __restrict__ kh,
    const _Float16* __restrict__ kl, const _Float16* __restrict__ vh,
    float* __restrict__ wso) {
    __shared__ __align__(16) _Float16 Vt[16 * SVT];
    int tid = threadIdx.x;
    int blk = blockIdx.x;                 // (b*8+h)*4 + ib
    int ib = blk & 3;
    int bh = blk >> 2;
    int b = bh >> 3, h = bh & 7;

    // stage V transposed: Vt[d][j] f16 (already f16 in global)
    {
        const _Float16* vr = vh + ((size_t)(b * 256 + tid)) * 128 + h * 16;
        f16x8 v0 = *(const f16x8*)vr;
        f16x8 v1 = *(const f16x8*)(vr + 8);
#pragma unroll
        for (int d = 0; d < 8; ++d) {
            Vt[d * SVT + tid] = v0[d];
            Vt[(8 + d) * SVT + tid] = v1[d];
        }
    }
    __syncthreads();

    int lane = tid & 63, w = tid >> 6;
    int ln = lane & 15, q = lane >> 4;
    int i0 = ib * 64 + w * 16;
    const f4 zero4 = { 0.f, 0.f, 0.f, 0.f };

    // B_Q: [Qh | Qh] across K=32 slots (d-half selected by q&1)
    f16x8 Bq;
    {
        f16x4 qa = *(const f16x4*)&qh[((size_t)(b * 256 + i0 + ln)) * 128 + h * 16 + (q & 1) * 8];
        f16x4 qb = *(const f16x4*)&qh[((size_t)(b * 256 + i0 + ln)) * 128 + h * 16 + (q & 1) * 8 + 4];
        f16x8 t;
        t[0] = qa[0]; t[1] = qa[1]; t[2] = qa[2]; t[3] = qa[3];
        t[4] = qb[0]; t[5] = qb[1]; t[6] = qb[2]; t[7] = qb[3];
        Bq = t;
    }

    // S^T = K · Q^T : A = [K_hi (q<2) | K_lo (q>=2)], 16 m-tiles over j
    f4 accs[16];
    const _Float16* kbase = (q < 2 ? kh : kl) + ((size_t)(b * 256)) * 128 + h * 16 + (q & 1) * 8;
    const float* bb = ws + OFF_BIAS + ((size_t)(bh * 256 + i0 + ln)) * 256 + q * 4;
    const float* tbb = ws + OFF_BIAS + ((size_t)bh) * 65536 + (i0 + ln);
#pragma unroll
    for (int mt = 0; mt < 16; ++mt) {
        f16x8 Ak = *(const f16x8*)&kbase[(size_t)(mt * 16 + ln) * 128];
        f4 s = __builtin_amdgcn_mfma_f32_16x16x32_f16(Ak, Bq, zero4, 0, 0, 0);
        f4 bias4;
        if ((mt >> 2) < ib) {
            // lower-triangle tile: read transposed (bias[j][i]); lanes span one 64B line per row
            const float* tb = tbb + (size_t)(mt * 16 + q * 4) * 256;
            bias4[0] = tb[0];
            bias4[1] = tb[256];
            bias4[2] = tb[512];
            bias4[3] = tb[768];
        } else {
            bias4 = *(const f4*)&bb[mt * 16];
        }
#pragma unroll
        for (int r = 0; r < 4; ++r) s[r] = fmaf(s[r], 0.25f, bias4[r]);
        accs[mt] = s;
    }

    // softmax over j (64 in-lane values + cross-q reduce; i = ln fixed per lane)
    float mx = accs[0][0];
#pragma unroll
    for (int mt = 0; mt < 16; ++mt)
#pragma unroll
        for (int r = 0; r < 4; ++r) mx = fmaxf(mx, accs[mt][r]);
    mx = fmaxf(mx, __shfl_xor(mx, 16));
    mx = fmaxf(mx, __shfl_xor(mx, 32));
    float nms = -mx * L2E_F;
    float l = 0.0f;
#pragma unroll
    for (int mt = 0; mt < 16; ++mt) {
#pragma unroll
        for (int r = 0; r < 4; ++r) {
            float p = __builtin_amdgcn_exp2f(fmaf(accs[mt][r], L2E_F, nms));
            accs[mt][r] = p;
            l += p;
        }
    }
    l += __shfl_xor(l, 16);
    l += __shfl_xor(l, 32);
    float inv = __builtin_amdgcn_rcpf(l);

    // O^T = V^T_perm · P^T  (kappa: in-lane P pack, permuted V read)
    f4 o = zero4;
#pragma unroll
    for (int ks = 0; ks < 8; ++ks) {
        u4 bp = { pkh2(accs[2 * ks][0], accs[2 * ks][1]),
                  pkh2(accs[2 * ks][2], accs[2 * ks][3]),
                  pkh2(accs[2 * ks + 1][0], accs[2 * ks + 1][1]),
                  pkh2(accs[2 * ks + 1][2], accs[2 * ks + 1][3]) };
        int vb = ln * SVT + 32 * ks + 4 * q;
        f16x4 lo4 = *(const f16x4*)&Vt[vb];
        f16x4 hi4 = *(const f16x4*)&Vt[vb + 16];
        f16x8 av;
        av[0] = lo4[0]; av[1] = lo4[1]; av[2] = lo4[2]; av[3] = lo4[3];
        av[4] = hi4[0]; av[5] = hi4[1]; av[6] = hi4[2]; av[7] = hi4[3];
        o = __builtin_amdgcn_mfma_f32_16x16x32_f16(av, __builtin_bit_cast(f16x8, bp), o, 0, 0, 0);
    }
    f4 res = o * inv;
    *(f4*)(wso + OFF_AO + ((size_t)(b * 256 + i0 + ln)) * 128 + h * 16 + q * 4) = res;
}

// ---------------- K_D: output projection (MFMA) — 128 blocks x 4 waves ----------------
__global__ __launch_bounds__(256) void k_out(
    const float* __restrict__ ws, const _Float16* __restrict__ wp,
    const float* __restrict__ bo, float* __restrict__ out) {
    int tid = threadIdx.x;
    int lane = tid & 63, ln = lane & 15, q = lane >> 4;
    int wid = blockIdx.x * 4 + (tid >> 6);       // 0..511
    int og = wid & 1, tg = wid >> 1;
    const _Float16* wpm = wp + UQKV + 3 * 32768;
    size_t tok = (size_t)(tg * 16 + ln);
    f4 cc[4];
    mfma_core64x16(ws + OFF_AO + tok * 128, wpm, og * 4, bo + og * 64, lane, cc);
#pragma unroll
    for (int mtl = 0; mtl < 4; ++mtl)
        *(f4*)(out + tok * 128 + og * 64 + mtl * 16 + q * 4) = cc[mtl];
}

extern "C" void kernel_launch(void* const* d_in, const int* in_sizes, int n_in,
                              void* d_out, int out_size, void* d_ws, size_t ws_size,
                              hipStream_t stream) {
    const float* x_pf   = (const float*)d_in[0];
    const float* x_feat = (const float*)d_in[1];
    const float* w0 = (const float*)d_in[2];
    const float* b0 = (const float*)d_in[3];
    const float* w1 = (const float*)d_in[4];
    const float* b1 = (const float*)d_in[5];
    const float* w2 = (const float*)d_in[6];
    const float* b2 = (const float*)d_in[7];
    const float* w3 = (const float*)d_in[8];
    const float* b3 = (const float*)d_in[9];
    const float* wq = (const float*)d_in[10];
    const float* wk = (const float*)d_in[11];
    const float* wv = (const float*)d_in[12];
    const float* wo = (const float*)d_in[13];
    const float* bq = (const float*)d_in[14];
    const float* bk = (const float*)d_in[15];
    const float* bv = (const float*)d_in[16];
    const float* bo = (const float*)d_in[17];
    float* ws  = (float*)d_ws;
    float* out = (float*)d_out;
    _Float16* wpack = (_Float16*)(ws + OFF_WPACK);
    _Float16* qh = (_Float16*)(ws + OFF_Q);
    _Float16* kh = qh + 524288;
    _Float16* kl = kh + 524288;
    _Float16* vh = kl + 524288;

    hipLaunchKernelGGL(k_prep, dim3(80), dim3(256), 0, stream,
                       w0, w1, w2, w3, wq, wk, wv, wo, x_pf, wpack, ws);
    hipLaunchKernelGGL(k_pair_qkv, dim3(384 + 2560), dim3(256), 0, stream,
                       ws, wpack, b0, b1, b2, b3, ws + OFF_BIAS,
                       x_feat, bq, bk, bv, qh, kh, kl, vh);
    hipLaunchKernelGGL(k_attn, dim3(512), dim3(256), 0, stream, ws, qh, kh, kl, vh, ws);
    hipLaunchKernelGGL(k_out, dim3(128), dim3(256), 0, stream, ws, wpack, bo, out);
}